// Round 20
// baseline (178.614 us; speedup 1.0000x reference)
//
#include <hip/hip_runtime.h>
#include <math.h>

#define BB 2
#define TT 1024
#define DD 1024
#define HH 16
#define KK 64
#define NBT 2048              // B*T
#define NE  2097152ULL        // B*T*D

typedef unsigned short u16;
typedef __attribute__((ext_vector_type(8))) short short8;   // 8 bf16 (4 VGPR)
typedef __attribute__((ext_vector_type(4))) short short4v;  // 4 bf16 (8B)
typedef __attribute__((ext_vector_type(4))) float f32x4;

__device__ __forceinline__ float bf2f(u16 u) {
  union { unsigned int i; float f; } v; v.i = ((unsigned int)u) << 16; return v.f;
}
__device__ __forceinline__ u16 f2bf(float x) {
  union { float f; unsigned int u; } v; v.f = x;
  unsigned int r = v.u + 0x7fffu + ((v.u >> 16) & 1u);
  return (u16)(r >> 16);
}
__device__ __forceinline__ f32x4 MFMA(short8 a, short8 b, f32x4 c) {
  return __builtin_amdgcn_mfma_f32_16x16x32_bf16(a, b, c, 0, 0, 0);
}
// XOR swizzle for [64 rows][128B] LDS tiles (G4: 128B rows are 32-way conflict)
__device__ __forceinline__ int swzb(int row, int kbyte) {
  return row * 128 + (kbyte ^ ((row & 7) << 4));
}
__device__ __forceinline__ void gload16(const void* g, void* l) {
  __builtin_amdgcn_global_load_lds((const __attribute__((address_space(1))) void*)g,
                                   (__attribute__((address_space(3))) void*)l, 16, 0, 0);
}

// ---------------- pre: small transposes + k1_xxx (flat grid 2256) ----------------
__global__ __launch_bounds__(256)
void pre(const float* __restrict__ W2, u16* __restrict__ W2t,
         const float* __restrict__ W1, u16* __restrict__ W1t,
         const float* __restrict__ wdec2, const float* __restrict__ a2,
         u16* __restrict__ wdec2t, u16* __restrict__ a2t,
         const float* __restrict__ wdec1, const float* __restrict__ a1,
         u16* __restrict__ wdec1t, u16* __restrict__ a1t,
         const float* __restrict__ x, const float* __restrict__ maa_x,
         u16* __restrict__ xxx_b) {
  __shared__ float tl[64][65];
  int idx = blockIdx.x;
  int tid = threadIdx.x;
  if (idx < 96) {
    int s = idx >> 4, d0 = (idx & 15) * 64;
    int c = tid & 63, r0 = (tid >> 6) * 8;
#pragma unroll
    for (int j = 0; j < 8; ++j)
      tl[r0 + j][c] = W2[(size_t)(s * 32 + r0 + j) * 1024 + d0 + c];
    __syncthreads();
    int d = tid >> 2, ms = (tid & 3) * 8;
    u16 o[8];
#pragma unroll
    for (int j = 0; j < 8; ++j) o[j] = f2bf(tl[ms + j][d]);
    *(short8*)(W2t + ((size_t)s * 1024 + d0 + d) * 32 + ms) = *(short8*)o;
  } else if (idx < 144) {
    int i = idx - 96;
    int k0 = (i & 15) * 64, n0 = (i >> 4) * 64;
    int r = tid >> 2, c0 = (tid & 3) * 16;
#pragma unroll
    for (int j = 0; j < 16; j += 4) {
      f32x4 v = *(const f32x4*)(W1 + (size_t)(k0 + r) * 192 + n0 + c0 + j);
      tl[r][c0 + j + 0] = v[0]; tl[r][c0 + j + 1] = v[1];
      tl[r][c0 + j + 2] = v[2]; tl[r][c0 + j + 3] = v[3];
    }
    __syncthreads();
    u16 o[16];
#pragma unroll
    for (int j = 0; j < 16; ++j) o[j] = f2bf(tl[c0 + j][r]);
    *(short8*)(W1t + (size_t)(n0 + r) * 1024 + k0 + c0) = *(short8*)(o);
    *(short8*)(W1t + (size_t)(n0 + r) * 1024 + k0 + c0 + 8) = *(short8*)(o + 8);
  } else if (idx < 176) {
    int i = idx - 144;
    int zz = i >> 4;
    const float* W = zz ? a2 : wdec2;
    u16* Wt = zz ? a2t : wdec2t;
    int n0 = (i & 15) * 64;
    int r = tid >> 2, c0 = (tid & 3) * 16;
#pragma unroll
    for (int j = 0; j < 16; j += 4) {
      f32x4 v = *(const f32x4*)(W + (size_t)r * 1024 + n0 + c0 + j);
      tl[r][c0 + j + 0] = v[0]; tl[r][c0 + j + 1] = v[1];
      tl[r][c0 + j + 2] = v[2]; tl[r][c0 + j + 3] = v[3];
    }
    __syncthreads();
    u16 o[16];
#pragma unroll
    for (int j = 0; j < 16; ++j) o[j] = f2bf(tl[c0 + j][r]);
    *(short8*)(Wt + (size_t)(n0 + r) * 64 + c0) = *(short8*)(o);
    *(short8*)(Wt + (size_t)(n0 + r) * 64 + c0 + 8) = *(short8*)(o + 8);
  } else if (idx < 208) {
    int i = idx - 176;
    int zz = i >> 4;
    const float* W = zz ? a1 : wdec1;
    u16* Wt = zz ? a1t : wdec1t;
    int k0 = (i & 15) * 64;
    int r = tid >> 2, c0 = (tid & 3) * 16;
#pragma unroll
    for (int j = 0; j < 16; j += 4) {
      f32x4 v = *(const f32x4*)(W + (size_t)(k0 + r) * 64 + c0 + j);
      tl[r][c0 + j + 0] = v[0]; tl[r][c0 + j + 1] = v[1];
      tl[r][c0 + j + 2] = v[2]; tl[r][c0 + j + 3] = v[3];
    }
    __syncthreads();
    u16 o[16];
#pragma unroll
    for (int j = 0; j < 16; ++j) o[j] = f2bf(tl[c0 + j][r]);
    *(short8*)(Wt + (size_t)r * 1024 + k0 + c0) = *(short8*)(o);
    *(short8*)(Wt + (size_t)r * 1024 + k0 + c0 + 8) = *(short8*)(o + 8);
  } else {
    int row = idx - 208;
    int t = row & (TT - 1);
    int d0 = tid * 4;
    size_t g = (size_t)row * DD + d0;
    f32x4 xc = *(const f32x4*)(x + g);
    f32x4 xl = {0.f, 0.f, 0.f, 0.f}, xr = {0.f, 0.f, 0.f, 0.f};
    if (t != 0) xl = *(const f32x4*)(x + g - DD);
    if (t != TT - 1) xr = *(const f32x4*)(x + g + DD);
    f32x4 mx = *(const f32x4*)(maa_x + d0);
    u16 o[4];
#pragma unroll
    for (int j = 0; j < 4; ++j)
      o[j] = f2bf(xc[j] + (0.5f * (xl[j] + xr[j]) - xc[j]) * mx[j]);
    *(short4v*)(xxx_b + g) = *(short4v*)o;
  }
}

// ---------------- hmix_g fused with big-5 W transposes (flat grid 1664) ----------------
__global__ __launch_bounds__(256)
void hmix_g(const float* __restrict__ W_r, const float* __restrict__ W_k,
            const float* __restrict__ W_v, const float* __restrict__ W_g,
            const float* __restrict__ W_o,
            u16* __restrict__ TR, u16* __restrict__ TK, u16* __restrict__ TV,
            u16* __restrict__ TG, u16* __restrict__ TO,
            const u16* __restrict__ xxx_b, const u16* __restrict__ W1t,
            float* __restrict__ P3) {
  __shared__ float tl[64][65];
  __shared__ u16 As[4096];  // 128x32
  __shared__ u16 Bs[2048];  // 64x32
  int idx = blockIdx.x;
  int tid = threadIdx.x;
  if (idx < 1280) {
    int z = idx >> 8, rem = idx & 255;
    const float* W = (z == 0) ? W_r : (z == 1) ? W_k : (z == 2) ? W_v : (z == 3) ? W_g : W_o;
    u16* Wt = (z == 0) ? TR : (z == 1) ? TK : (z == 2) ? TV : (z == 3) ? TG : TO;
    int k0 = (rem & 15) * 64, n0 = (rem >> 4) * 64;
    int r = tid >> 2, c0 = (tid & 3) * 16;
#pragma unroll
    for (int j = 0; j < 16; j += 4) {
      f32x4 v = *(const f32x4*)(W + (size_t)(k0 + r) * 1024 + n0 + c0 + j);
      tl[r][c0 + j + 0] = v[0]; tl[r][c0 + j + 1] = v[1];
      tl[r][c0 + j + 2] = v[2]; tl[r][c0 + j + 3] = v[3];
    }
    __syncthreads();
    u16 o[16];
#pragma unroll
    for (int j = 0; j < 16; ++j) o[j] = f2bf(tl[c0 + j][r]);
    *(short8*)(Wt + (size_t)(n0 + r) * 1024 + k0 + c0) = *(short8*)(o);
    *(short8*)(Wt + (size_t)(n0 + r) * 1024 + k0 + c0 + 8) = *(short8*)(o + 8);
    return;
  }
  int i = idx - 1280;                 // 0..383
  int n0 = (i % 3) * 64;
  int q = i / 3;                      // 0..127
  int m0 = (q & 15) * 128;
  int kb = q >> 4;                    // 0..7
  int w = tid >> 6, lane = tid & 63;
  int mq = w >> 1, nq = w & 1;
  f32x4 acc[4][2];
#pragma unroll
  for (int ii = 0; ii < 4; ++ii)
#pragma unroll
    for (int j = 0; j < 2; ++j) acc[ii][j] = {0.f, 0.f, 0.f, 0.f};
  for (int t = 0; t < 4; ++t) {
    int k0 = kb * 128 + t * 32;
#pragma unroll
    for (int c2 = 0; c2 < 2; ++c2) {
      int ch = w * 2 + c2;
      int row = ch * 16 + (lane >> 2);
      gload16(xxx_b + (size_t)(m0 + row) * 1024 + k0 + (lane & 3) * 8, As + ch * 512);
    }
    {
      int row = w * 16 + (lane >> 2);
      gload16(W1t + (size_t)(n0 + row) * 1024 + k0 + (lane & 3) * 8, Bs + w * 512);
    }
    __syncthreads();
    short8 a[4], b[2];
#pragma unroll
    for (int mf = 0; mf < 4; ++mf)
      a[mf] = *(const short8*)(As + (mq * 64 + mf * 16 + (lane & 15)) * 32 + (lane >> 4) * 8);
#pragma unroll
    for (int nf = 0; nf < 2; ++nf)
      b[nf] = *(const short8*)(Bs + (nq * 32 + nf * 16 + (lane & 15)) * 32 + (lane >> 4) * 8);
#pragma unroll
    for (int mf = 0; mf < 4; ++mf)
#pragma unroll
      for (int nf = 0; nf < 2; ++nf) acc[mf][nf] = MFMA(a[mf], b[nf], acc[mf][nf]);
    __syncthreads();
  }
#pragma unroll
  for (int mf = 0; mf < 4; ++mf) {
#pragma unroll
    for (int nf = 0; nf < 2; ++nf) {
      int mb = m0 + mq * 64 + mf * 16 + (lane >> 4) * 4;
      int n = n0 + nq * 32 + nf * 16 + (lane & 15);
#pragma unroll
      for (int r = 0; r < 4; ++r)
        P3[(size_t)kb * 393216 + (size_t)(mb + r) * 192 + n] = acc[mf][nf][r];
    }
  }
}

// ---------------- reduce 8 partials -> tanh -> bf16 (hmix) ----------------
__global__ __launch_bounds__(256)
void reduce8b(const float* __restrict__ P, u16* __restrict__ C, int total) {
  size_t i = (size_t)blockIdx.x * 256 + threadIdx.x;
  float s = 0.f;
#pragma unroll
  for (int kb = 0; kb < 8; ++kb) s += P[(size_t)kb * total + i];
  C[i] = f2bf(tanhf(s));
}

// ---------------- fused pair reduce -> bf16 ----------------
__global__ __launch_bounds__(256)
void reduce8_pairb(const float* __restrict__ Pw, const float* __restrict__ Pa,
                   u16* __restrict__ hdec_b, u16* __restrict__ ha_b) {
  int z = blockIdx.y;
  size_t i = (size_t)blockIdx.x * 256 + threadIdx.x;
  const float* P = z ? Pa : Pw;
  float s = 0.f;
#pragma unroll
  for (int kb = 0; kb < 8; ++kb) s += P[(size_t)kb * 131072 + i];
  if (z) ha_b[i] = f2bf(s);
  else hdec_b[i] = f2bf(tanhf(s));
}

// ---------------- mixg v3: MFMA mix + LDS round-trip + coalesced bf16 epilogue ----------------
__global__ __launch_bounds__(256)
void mixg(const u16* __restrict__ hmixb, const u16* __restrict__ W2t,
          const float* __restrict__ x,
          const float* __restrict__ maa_w, const float* __restrict__ maa_k,
          const float* __restrict__ maa_v, const float* __restrict__ maa_r,
          const float* __restrict__ maa_g, const float* __restrict__ maa_a,
          u16* __restrict__ xw_b, u16* __restrict__ xa_b,
          u16* __restrict__ xk_b, u16* __restrict__ xv_b,
          u16* __restrict__ xr_b, u16* __restrict__ xg_b) {
  __shared__ u16 shm[16384];
  u16* As = shm;
  u16* Bs = shm + 4096;
  u16* mixt = shm;
  int s = blockIdx.z;
  int m0 = blockIdx.y * 128, n0 = blockIdx.x * 128;
  int tid = threadIdx.x, w = tid >> 6, lane = tid & 63;
  int mq = w >> 1, nq = w & 1;
#pragma unroll
  for (int c2 = 0; c2 < 2; ++c2) {
    int ch = w * 2 + c2;
    int row = ch * 16 + (lane >> 2);
    gload16(hmixb + (size_t)(m0 + row) * 192 + s * 32 + (lane & 3) * 8, As + ch * 512);
    gload16(W2t + ((size_t)s * 1024 + n0 + row) * 32 + (lane & 3) * 8, Bs + ch * 512);
  }
  __syncthreads();
  short8 a[4], b[4];
#pragma unroll
  for (int mf = 0; mf < 4; ++mf)
    a[mf] = *(const short8*)(As + (mq * 64 + mf * 16 + (lane & 15)) * 32 + (lane >> 4) * 8);
#pragma unroll
  for (int nf = 0; nf < 4; ++nf)
    b[nf] = *(const short8*)(Bs + (nq * 64 + nf * 16 + (lane & 15)) * 32 + (lane >> 4) * 8);
  f32x4 acc[4][4];
#pragma unroll
  for (int mf = 0; mf < 4; ++mf)
#pragma unroll
    for (int nf = 0; nf < 4; ++nf) {
      f32x4 z = {0.f, 0.f, 0.f, 0.f};
      acc[mf][nf] = MFMA(a[mf], b[nf], z);
    }
  __syncthreads();
#pragma unroll
  for (int mf = 0; mf < 4; ++mf) {
#pragma unroll
    for (int nf = 0; nf < 4; ++nf) {
      int col = nq * 64 + nf * 16 + (lane & 15);
#pragma unroll
      for (int r = 0; r < 4; ++r) {
        int row = mq * 64 + mf * 16 + (lane >> 4) * 4 + r;
        mixt[row * 128 + col] = f2bf(acc[mf][nf][r]);
      }
    }
  }
  __syncthreads();
  const float* maa = (s == 0) ? maa_w : (s == 1) ? maa_k : (s == 2) ? maa_v
                    : (s == 3) ? maa_r : (s == 4) ? maa_g : maa_a;
  u16* dst = (s == 0) ? xw_b : (s == 1) ? xk_b : (s == 2) ? xv_b
            : (s == 3) ? xr_b : (s == 4) ? xg_b : xa_b;
  int cg = tid & 15;
  int rowg = tid >> 4;
  int d0 = n0 + cg * 8;
  f32x4 ma0 = *(const f32x4*)(maa + d0);
  f32x4 ma1 = *(const f32x4*)(maa + d0 + 4);
#pragma unroll
  for (int rr = 0; rr < 8; ++rr) {
    int row = rr * 16 + rowg;
    int m = m0 + row;
    int t = m & (TT - 1);
    size_t g = (size_t)m * DD + d0;
    f32x4 xc0 = *(const f32x4*)(x + g);
    f32x4 xc1 = *(const f32x4*)(x + g + 4);
    f32x4 xl0 = {0.f, 0.f, 0.f, 0.f}, xl1 = {0.f, 0.f, 0.f, 0.f};
    f32x4 xr0 = {0.f, 0.f, 0.f, 0.f}, xr1 = {0.f, 0.f, 0.f, 0.f};
    if (t != 0) { xl0 = *(const f32x4*)(x + g - DD); xl1 = *(const f32x4*)(x + g - DD + 4); }
    if (t != TT - 1) { xr0 = *(const f32x4*)(x + g + DD); xr1 = *(const f32x4*)(x + g + DD + 4); }
    short8 mv = *(const short8*)(mixt + row * 128 + cg * 8);
    u16 o[8];
#pragma unroll
    for (int j = 0; j < 8; ++j) {
      float xcj = (j < 4) ? xc0[j & 3] : xc1[j & 3];
      float xlj = (j < 4) ? xl0[j & 3] : xl1[j & 3];
      float xrj = (j < 4) ? xr0[j & 3] : xr1[j & 3];
      float maj = (j < 4) ? ma0[j & 3] : ma1[j & 3];
      float dx = 0.5f * (xlj + xrj) - xcj;
      o[j] = f2bf(xcj + dx * (maj + bf2f((u16)mv[j])));
    }
    *(short8*)(dst + g) = *(short8*)o;
  }
}

// ---------------- fused 4-way bf16 MFMA projection GEMM + skinny LoRA-down ----------------
__global__ __launch_bounds__(256)
void gemm_bf4(const u16* __restrict__ xr, const u16* __restrict__ xk,
              const u16* __restrict__ xv, const u16* __restrict__ xg,
              const u16* __restrict__ WtR, const u16* __restrict__ WtK,
              const u16* __restrict__ WtV, const u16* __restrict__ WtG,
              u16* __restrict__ rbuf, u16* __restrict__ kbuf,
              u16* __restrict__ vT, u16* __restrict__ gb,
              const u16* __restrict__ xw_b, const u16* __restrict__ wdec1t,
              float* __restrict__ PpartW,
              const u16* __restrict__ xa_b, const u16* __restrict__ a1t,
              float* __restrict__ PpartA) {
  __shared__ u16 As[2][4096];
  __shared__ u16 Bs[2][2048];
  int wgid = blockIdx.x;
  int tid = threadIdx.x, w = tid >> 6, lane = tid & 63;
  int mq = w >> 1, nq = w & 1;
  if (wgid >= 1024) {
    int i = wgid - 1024;
    int m0 = (i & 15) * 128;
    int kb = (i >> 4) & 7;
    int z = i >> 7;
    const u16* A = z ? xa_b : xw_b;
    const u16* Bt = z ? a1t : wdec1t;
    float* P = z ? PpartA : PpartW;
    f32x4 acc[4][2];
#pragma unroll
    for (int ii = 0; ii < 4; ++ii)
#pragma unroll
      for (int j = 0; j < 2; ++j) acc[ii][j] = {0.f, 0.f, 0.f, 0.f};
    for (int t = 0; t < 4; ++t) {
      int k0 = kb * 128 + t * 32;
#pragma unroll
      for (int c2 = 0; c2 < 2; ++c2) {
        int ch = w * 2 + c2;
        int row = ch * 16 + (lane >> 2);
        gload16(A + (size_t)(m0 + row) * 1024 + k0 + (lane & 3) * 8, As[0] + ch * 512);
      }
      {
        int row = w * 16 + (lane >> 2);
        gload16(Bt + (size_t)row * 1024 + k0 + (lane & 3) * 8, Bs[0] + w * 512);
      }
      __syncthreads();
      short8 a[4], b[2];
#pragma unroll
      for (int mf = 0; mf < 4; ++mf)
        a[mf] = *(const short8*)(As[0] + (mq * 64 + mf * 16 + (lane & 15)) * 32 + (lane >> 4) * 8);
#pragma unroll
      for (int nf = 0; nf < 2; ++nf)
        b[nf] = *(const short8*)(Bs[0] + (nq * 32 + nf * 16 + (lane & 15)) * 32 + (lane >> 4) * 8);
#pragma unroll
      for (int mf = 0; mf < 4; ++mf)
#pragma unroll
        for (int nf = 0; nf < 2; ++nf) acc[mf][nf] = MFMA(a[mf], b[nf], acc[mf][nf]);
      __syncthreads();
    }
#pragma unroll
    for (int mf = 0; mf < 4; ++mf) {
#pragma unroll
      for (int nf = 0; nf < 2; ++nf) {
        int mb = m0 + mq * 64 + mf * 16 + (lane >> 4) * 4;
        int n = nq * 32 + nf * 16 + (lane & 15);
#pragma unroll
        for (int r = 0; r < 4; ++r)
          P[(size_t)kb * 131072 + (size_t)(mb + r) * 64 + n] = acc[mf][nf][r];
      }
    }
    return;
  }
  int xcd = wgid & 7, idx = wgid >> 3;
  int z = xcd >> 1, mhalf = xcd & 1;
  int mloc = idx & 7, nt = idx >> 3;
  int m0 = (mhalf * 8 + mloc) * 128;
  int n0 = nt * 64;
  const u16* A = (z == 0) ? xr : (z == 1) ? xk : (z == 2) ? xv : xg;
  const u16* Bt = (z == 0) ? WtR : (z == 1) ? WtK : (z == 2) ? WtV : WtG;
  int arow0 = (w * 2) * 16 + (lane >> 2);
  int arow1 = (w * 2 + 1) * 16 + (lane >> 2);
  int brow = w * 16 + (lane >> 2);
  int kc = (lane & 3) * 8;
  f32x4 acc[4][2];
#pragma unroll
  for (int i = 0; i < 4; ++i)
#pragma unroll
    for (int j = 0; j < 2; ++j) acc[i][j] = {0.f, 0.f, 0.f, 0.f};
  gload16(A + (size_t)(m0 + arow0) * 1024 + kc, As[0] + (w * 2) * 512);
  gload16(A + (size_t)(m0 + arow1) * 1024 + kc, As[0] + (w * 2 + 1) * 512);
  gload16(Bt + (size_t)(n0 + brow) * 1024 + kc, Bs[0] + w * 512);
  __syncthreads();
  for (int t = 0; t < 32; ++t) {
    int cur = t & 1;
    if (t < 31) {
      int kn = (t + 1) * 32;
      gload16(A + (size_t)(m0 + arow0) * 1024 + kn + kc, As[cur ^ 1] + (w * 2) * 512);
      gload16(A + (size_t)(m0 + arow1) * 1024 + kn + kc, As[cur ^ 1] + (w * 2 + 1) * 512);
      gload16(Bt + (size_t)(n0 + brow) * 1024 + kn + kc, Bs[cur ^ 1] + w * 512);
    }
    short8 a[4], b[2];
#pragma unroll
    for (int mf = 0; mf < 4; ++mf)
      a[mf] = *(const short8*)(As[cur] + (mq * 64 + mf * 16 + (lane & 15)) * 32 + (lane >> 4) * 8);
#pragma unroll
    for (int nf = 0; nf < 2; ++nf)
      b[nf] = *(const short8*)(Bs[cur] + (nq * 32 + nf * 16 + (lane & 15)) * 32 + (lane >> 4) * 8);
#pragma unroll
    for (int mf = 0; mf < 4; ++mf)
#pragma unroll
      for (int nf = 0; nf < 2; ++nf) acc[mf][nf] = MFMA(a[mf], b[nf], acc[mf][nf]);
    __syncthreads();
  }
#pragma unroll
  for (int mf = 0; mf < 4; ++mf) {
#pragma unroll
    for (int nf = 0; nf < 2; ++nf) {
      int mb = m0 + mq * 64 + mf * 16 + (lane >> 4) * 4;
      int n = n0 + nq * 32 + nf * 16 + (lane & 15);
      if (z == 2) {  // VTB: vT[b*H+h][k][t] bf16
        u16 o[4];
#pragma unroll
        for (int r = 0; r < 4; ++r) o[r] = f2bf(acc[mf][nf][r]);
        int b2 = mb >> 10, t = mb & 1023;
        *(short4v*)(vT + (((size_t)(b2 * HH + (n >> 6))) * KK + (n & 63)) * TT + t) = *(short4v*)o;
      } else if (z == 3) {  // gate: silu -> bf16 flat
#pragma unroll
        for (int r = 0; r < 4; ++r) {
          int m = mb + r;
          float v = acc[mf][nf][r];
          gb[(size_t)m * 1024 + n] = f2bf(v / (1.f + __expf(-v)));
        }
      } else {  // HEADB bf16 head layout
        u16* C = (z == 0) ? rbuf : kbuf;
#pragma unroll
        for (int r = 0; r < 4; ++r) {
          int m = mb + r;
          int b2 = m >> 10, t = m & 1023;
          C[(((size_t)(b2 * HH + (n >> 6))) * TT + t) * KK + (n & 63)] = f2bf(acc[mf][nf][r]);
        }
      }
    }
  }
}

// ---------------- W_o bf16 MFMA GEMM (128x64, BK=32 dbuf, XCD-partitioned 256 blocks) ----------------
__global__ __launch_bounds__(256)
void gemm_bfo(const u16* __restrict__ A, const u16* __restrict__ Bt,
              float* __restrict__ C) {
  __shared__ u16 As[2][4096];
  __shared__ u16 Bs[2][2048];
  int wgid = blockIdx.x;
  int xcd = wgid & 7, idx = wgid >> 3;
  int mloc = idx & 1, nt = idx >> 1;
  int m0 = (xcd * 2 + mloc) * 128;
  int n0 = nt * 64;
  int tid = threadIdx.x, w = tid >> 6, lane = tid & 63;
  int mq = w >> 1, nq = w & 1;
  int arow0 = (w * 2) * 16 + (lane >> 2);
  int arow1 = (w * 2 + 1) * 16 + (lane >> 2);
  int brow = w * 16 + (lane >> 2);
  int kc = (lane & 3) * 8;
  f32x4 acc[4][2];
#pragma unroll
  for (int i = 0; i < 4; ++i)
#pragma unroll
    for (int j = 0; j < 2; ++j) acc[i][j] = {0.f, 0.f, 0.f, 0.f};
  gload16(A + (size_t)(m0 + arow0) * 1024 + kc, As[0] + (w * 2) * 512);
  gload16(A + (size_t)(m0 + arow1) * 1024 + kc, As[0] + (w * 2 + 1) * 512);
  gload16(Bt + (size_t)(n0 + brow) * 1024 + kc, Bs[0] + w * 512);
  __syncthreads();
  for (int t = 0; t < 32; ++t) {
    int cur = t & 1;
    if (t < 31) {
      int kn = (t + 1) * 32;
      gload16(A + (size_t)(m0 + arow0) * 1024 + kn + kc, As[cur ^ 1] + (w * 2) * 512);
      gload16(A + (size_t)(m0 + arow1) * 1024 + kn + kc, As[cur ^ 1] + (w * 2 + 1) * 512);
      gload16(Bt + (size_t)(n0 + brow) * 1024 + kn + kc, Bs[cur ^ 1] + w * 512);
    }
    short8 a[4], b[2];
#pragma unroll
    for (int mf = 0; mf < 4; ++mf)
      a[mf] = *(const short8*)(As[cur] + (mq * 64 + mf * 16 + (lane & 15)) * 32 + (lane >> 4) * 8);
#pragma unroll
    for (int nf = 0; nf < 2; ++nf)
      b[nf] = *(const short8*)(Bs[cur] + (nq * 32 + nf * 16 + (lane & 15)) * 32 + (lane >> 4) * 8);
#pragma unroll
    for (int mf = 0; mf < 4; ++mf)
#pragma unroll
      for (int nf = 0; nf < 2; ++nf) acc[mf][nf] = MFMA(a[mf], b[nf], acc[mf][nf]);
    __syncthreads();
  }
#pragma unroll
  for (int mf = 0; mf < 4; ++mf) {
#pragma unroll
    for (int nf = 0; nf < 2; ++nf) {
      int mb = m0 + mq * 64 + mf * 16 + (lane >> 4) * 4;
      int n = n0 + nq * 32 + nf * 16 + (lane & 15);
#pragma unroll
      for (int r = 0; r < 4; ++r)
        C[(size_t)(mb + r) * 1024 + n] = acc[mf][nf][r];
    }
  }
}

// ---------------- gemm_k2b: dual K=64 bf16 MFMA LoRA-up ----------------
__global__ __launch_bounds__(256)
void gemm_k2b(const u16* __restrict__ A0, const u16* __restrict__ B0t,
              float* __restrict__ C0, const float* __restrict__ bias0,
              const u16* __restrict__ A1, const u16* __restrict__ B1t,
              float* __restrict__ C1, const float* __restrict__ bias1) {
  __shared__ u16 As[8192];  // [2 ks][128 rows][32 k]
  __shared__ u16 Bs[4096];  // [2 ks][64 rows][32 k]
  int z = blockIdx.z;
  const u16* A = z ? A1 : A0;
  const u16* Bt = z ? B1t : B0t;
  float* C = z ? C1 : C0;
  const float* bias = z ? bias1 : bias0;
  int n0 = blockIdx.x * 64, m0 = blockIdx.y * 128;
  int tid = threadIdx.x, w = tid >> 6, lane = tid & 63;
  int mq = w >> 1, nq = w & 1;
#pragma unroll
  for (int j = 0; j < 4; ++j) {
    int q = w * 4 + j;
    int ks = q >> 3, rg = q & 7;
    int row = rg * 16 + (lane >> 2);
    int kc = ks * 32 + (lane & 3) * 8;
    gload16(A + (size_t)(m0 + row) * 64 + kc, As + q * 512);
  }
#pragma unroll
  for (int j = 0; j < 2; ++j) {
    int q = w * 2 + j;
    int ks = q >> 2, rg = q & 3;
    int row = rg * 16 + (lane >> 2);
    int kc = ks * 32 + (lane & 3) * 8;
    gload16(Bt + (size_t)(n0 + row) * 64 + kc, Bs + q * 512);
  }
  __syncthreads();
  f32x4 acc[4][2];
#pragma unroll
  for (int i = 0; i < 4; ++i)
#pragma unroll
    for (int j = 0; j < 2; ++j) acc[i][j] = {0.f, 0.f, 0.f, 0.f};
#pragma unroll
  for (int ks = 0; ks < 2; ++ks) {
    short8 a[4], b[2];
#pragma unroll
    for (int mf = 0; mf < 4; ++mf)
      a[mf] = *(const short8*)(As + ks * 4096 + (mq * 64 + mf * 16 + (lane & 15)) * 32 + (lane >> 4) * 8);
#pragma unroll
    for (int nf = 0; nf < 2; ++nf)
      b[nf] = *(const short8*)(Bs + ks * 2048 + (nq * 32 + nf * 16 + (lane & 15)) * 32 + (lane >> 4) * 8);
#pragma unroll
    for (int mf = 0; mf < 4; ++mf)
#pragma unroll
      for (int nf = 0; nf < 2; ++nf) acc[mf][nf] = MFMA(a[mf], b[nf], acc[mf][nf]);
  }
#pragma unroll
  for (int mf = 0; mf < 4; ++mf) {
#pragma unroll
    for (int nf = 0; nf < 2; ++nf) {
      int mb = m0 + mq * 64 + mf * 16 + (lane >> 4) * 4;
      int n = n0 + nq * 32 + nf * 16 + (lane & 15);
      float bv = bias[n];
#pragma unroll
      for (int r = 0; r < 4; ++r) {
        int m = mb + r;
        int b2 = m >> 10, t = m & 1023;
        float vv = acc[mf][nf][r] + bv;
        if (z) vv = 1.f / (1.f + expf(-vv));
        C[(((size_t)(b2 * HH + (n >> 6))) * TT + t) * KK + (n & 63)] = vv;
      }
    }
  }
}

// ---------------- k4k5: fused kk-normalize (idx<8192) + wh/partials (idx>=8192) ----------------
__global__ __launch_bounds__(256)
void k4k5(u16* __restrict__ kbuf, u16* __restrict__ kkbuf, u16* __restrict__ kkibuf,
          const float* __restrict__ iclr, const float* __restrict__ k_k,
          const float* __restrict__ k_a,
          const float* __restrict__ csf, float* __restrict__ csbs,
          float* __restrict__ part) {
  int idx = blockIdx.x;
  int tid = threadIdx.x;
  if (idx < 8192) {
    int gid = idx * 4 + (tid >> 6);
    int lane = tid & 63;
    size_t base = (size_t)gid * 64 + lane;
    int h = (gid >> 10) & (HH - 1);
    int d = h * 64 + lane;
    float kv = bf2f(kbuf[base]);
    float ic = iclr[base];
    float kkh = kv * k_k[d];
    float ss = kkh * kkh;
#pragma unroll
    for (int off = 32; off > 0; off >>= 1) ss += __shfl_xor(ss, off);
    float nrm = fmaxf(sqrtf(ss), 1e-12f);
    float kkv = kkh / nrm;
    kkbuf[base] = f2bf(kkv);
    kkibuf[base] = f2bf(kkv * ic);
    kbuf[base] = f2bf(kv * (1.f + (ic - 1.f) * k_a[d]));
  } else {
    int bc = (idx - 8192) * 4 + (tid >> 6);
    int bh = bc >> 4, c = bc & 15;
    int lane = tid & 63;
    size_t base = (size_t)bh * TT * KK + (size_t)c * 64 * KK + lane;
    float p = 0.f;
    for (int i = 0; i < 64; ++i) {
      float wh = -expf(csf[base + (size_t)i * KK]);
      csbs[base + (size_t)i * KK] = wh;
      p += wh;
    }
    part[((size_t)bh * 16 + c) * 64 + lane] = p;
  }
}

// ---------------- attention tile helpers (bf16 MFMA, T5 setprio on MFMA clusters) ----------------
struct SReg { short8 a0, a1, b0, b1; };
template <int RSA, int RSB>
__device__ __forceinline__ void sload(const u16* ka, const u16* vb, SReg& r) {
  int t0 = threadIdx.x, t1 = threadIdx.x + 256;
  r.a0 = *(const short8*)(ka + (size_t)(t0 >> 3) * RSA + (t0 & 7) * 8);
  r.a1 = *(const short8*)(ka + (size_t)(t1 >> 3) * RSA + (t1 & 7) * 8);
  r.b0 = *(const short8*)(vb + (size_t)(t0 >> 3) * RSB + (t0 & 7) * 8);
  r.b1 = *(const short8*)(vb + (size_t)(t1 >> 3) * RSB + (t1 & 7) * 8);
}
__device__ __forceinline__ void swrite(u16* Kt, u16* Vt, const SReg& r) {
  int t0 = threadIdx.x, t1 = threadIdx.x + 256;
  *(short8*)((char*)Kt + swzb(t0 >> 3, (t0 & 7) * 16)) = r.a0;
  *(short8*)((char*)Kt + swzb(t1 >> 3, (t1 & 7) * 16)) = r.a1;
  *(short8*)((char*)Vt + swzb(t0 >> 3, (t0 & 7) * 16)) = r.b0;
  *(short8*)((char*)Vt + swzb(t1 >> 3, (t1 & 7) * 16)) = r.b1;
}
template <int MASK>  // 0 none, 1 jl<il, 2 jl>il, 3 jl<=il
__device__ __forceinline__ void store_S(const f32x4 s[4], u16* St, int lane, int w) {
  int ig0 = w * 16 + (lane >> 4) * 4;
#pragma unroll
  for (int jf = 0; jf < 4; ++jf) {
    int jl = jf * 16 + (lane & 15);
#pragma unroll
    for (int r = 0; r < 4; ++r) {
      int il = ig0 + r;
      float v = s[jf][r];
      if (MASK == 1 && !(jl < il)) v = 0.f;
      if (MASK == 2 && !(jl > il)) v = 0.f;
      if (MASK == 3 && !(jl <= il)) v = 0.f;
      *(u16*)((char*)St + swzb(il, jl * 2)) = f2bf(v);
    }
  }
}
__device__ __forceinline__ void smm(short8 a0, short8 a1, const u16* Kt, f32x4 s[4], int lane) {
  __builtin_amdgcn_s_setprio(1);
#pragma unroll
  for (int jf = 0; jf < 4; ++jf) {
    f32x4 z = {0.f, 0.f, 0.f, 0.f};
    short8 kb0 = *(const short8*)((const char*)Kt + swzb(jf * 16 + (lane & 15), (lane >> 4) * 16));
    z = MFMA(a0, kb0, z);
    short8 kb1 = *(const short8*)((const char*)Kt + swzb(jf * 16 + (lane & 15), 64 + (lane >> 4) * 16));
    z = MFMA(a1, kb1, z);
    s[jf] = z;
  }
  __builtin_amdgcn_s_setprio(0);
}
__device__ __forceinline__ void pv(const u16* St, const u16* Vt, f32x4 acc[4], int lane, int w) {
  __builtin_amdgcn_s_setprio(1);
#pragma unroll
  for (int ks = 0; ks < 2; ++ks) {
    short8 a = *(const short8*)((const char*)St + swzb(w * 16 + (lane & 15), ks * 64 + (lane >> 4) * 16));
#pragma unroll
    for (int cf = 0; cf < 4; ++cf) {
      short8 b = *(const short8*)((const char*)Vt + swzb(cf * 16 + (lane & 15), ks * 64 + (lane >> 4) * 16));
      acc[cf] = MFMA(a, b, acc[cf]);
    }
  }
  __builtin_amdgcn_s_setprio(0);
}

// ---------------- K6: pass 1, fwd/bwd split (wg<512 fwd, 512..1023 bwd, >=1024 k5c) ----------------
__global__ __launch_bounds__(256)
void k6_pass1(const u16* __restrict__ kk, const u16* __restrict__ kki,
              const u16* __restrict__ vT, u16* __restrict__ vfT, u16* __restrict__ vbT,
              const float* __restrict__ csbs, const float* __restrict__ part,
              const u16* __restrict__ rb, const u16* __restrict__ kb,
              u16* __restrict__ rfb, u16* __restrict__ rbb,
              u16* __restrict__ kfb, u16* __restrict__ kbw) {
  __shared__ u16 Kt[2][4096], Vt[2][4096], St[4096];
  int wg = blockIdx.x;
  int tid = threadIdx.x;
  if (wg >= 1024) {
    // k5c: prefix + cs recurrence + clip + factored operands
    int bc = (wg - 1024) * 4 + (tid >> 6);
    int bh = bc >> 4, c = bc & 15;
    int lane = tid & 63;
    size_t hb = (size_t)bh * TT * KK;
    float run = 0.f, csb512 = 0.f;
    for (int cc = 0; cc < 16; ++cc) {
      float pvv = part[((size_t)bh * 16 + cc) * 64 + lane];
      if (cc < c) run += pvv;
      if (cc < 8) csb512 += pvv;
    }
    float wh512 = csbs[hb + (size_t)512 * KK + lane];
    float cs512 = csb512 + wh512;
    size_t base = hb + (size_t)c * 64 * KK + lane;
    float cs = run;
    for (int i = 0; i < 64; ++i) {
      size_t g = base + (size_t)i * KK;
      float wh = csbs[g];
      cs += wh;
      float cf = fminf(fmaxf(cs - cs512, -60.f), 60.f);
      float cb = fminf(fmaxf((cs - wh) - csb512, -60.f), 60.f);
      float rvf = bf2f(rb[g]);
      float kvf = bf2f(kb[g]);
      rfb[g] = f2bf(rvf * __expf(cf));
      kfb[g] = f2bf(kvf * __expf(-cf));
      rbb[g] = f2bf(rvf * __expf(-cb));
      kbw[g] = f2bf(kvf * __expf(cb));
    }
    return;
  }
  int dir = (wg >= 512);
  int w0 = dir ? wg - 512 : wg;
  int bh = w0 & 31, it = w0 >> 5, i0 = it * 64;
  size_t hb = (size_t)bh * 65536;
  int w = tid >> 6, lane = tid & 63;
  int iw = i0 + w * 16;
  int row = iw + (lane & 15), ko = (lane >> 4) * 8;
  short8 a0 = *(const short8*)(kki + hb + (size_t)row * 64 + ko);
  short8 a1 = *(const short8*)(kki + hb + (size_t)row * 64 + 32 + ko);
  f32x4 acc[4];
#pragma unroll
  for (int c = 0; c < 4; ++c) acc[c] = {0.f, 0.f, 0.f, 0.f};
  int s0 = dir ? it : 0;
  int nph = dir ? 16 - it : it + 1;
  SReg sr, nx;
  sload<64, 1024>(kk + hb + (size_t)s0 * 4096, vT + hb + s0 * 64, sr);
  swrite(Kt[0], Vt[0], sr);
  __syncthreads();
  for (int p = 0; p < nph; ++p) {
    int s = s0 + p;
    int cur = p & 1;
    if (p < nph - 1)
      sload<64, 1024>(kk + hb + (size_t)(s + 1) * 4096, vT + hb + (s + 1) * 64, nx);
    f32x4 sv[4];
    smm(a0, a1, Kt[cur], sv, lane);
    if (s == it) {
      if (dir) store_S<2>(sv, St, lane, w);
      else store_S<1>(sv, St, lane, w);
    } else {
      store_S<0>(sv, St, lane, w);
    }
    pv(St, Vt[cur], acc, lane, w);
    if (p < nph - 1) swrite(Kt[cur ^ 1], Vt[cur ^ 1], nx);
    __syncthreads();
  }
  u16* dst = dir ? vbT : vfT;
#pragma unroll
  for (int cf = 0; cf < 4; ++cf) {
    int c = cf * 16 + (lane & 15);
    int i = iw + (lane >> 4) * 4;
    size_t g = hb + (size_t)c * 1024 + i;
    short4v vv = *(const short4v*)(vT + g);
    u16 o1[4];
#pragma unroll
    for (int r = 0; r < 4; ++r)
      o1[r] = f2bf(bf2f((u16)vv[r]) - acc[cf][r]);
    *(short4v*)(dst + g) = *(short4v*)o1;
  }
}

// ---------------- K7: pass 2, fwd/bwd split -> partial f32 outputs yf/yb ----------------
__global__ __launch_bounds__(256)
void k7_pass2(const u16* __restrict__ rfb, const u16* __restrict__ rbb,
              const u16* __restrict__ kfb, const u16* __restrict__ kbw,
              const u16* __restrict__ vfT, const u16* __restrict__ vbT,
              float* __restrict__ yf, float* __restrict__ yb) {
  __shared__ u16 Kt[2][4096], Vt[2][4096], St[4096];
  int wg = blockIdx.x;
  int dir = (wg >= 512);
  int w0 = dir ? wg - 512 : wg;
  int bh = w0 & 31, it = w0 >> 5, i0 = it * 64;
  size_t hb = (size_t)bh * 65536;
  int tid = threadIdx.x, w = tid >> 6, lane = tid & 63;
  int iw = i0 + w * 16;
  int row = iw + (lane & 15), ko = (lane >> 4) * 8;
  const u16* rp = dir ? rbb : rfb;
  const u16* kp = dir ? kbw : kfb;
  const u16* vp = dir ? vbT : vfT;
  short8 a0 = *(const short8*)(rp + hb + (size_t)row * 64 + ko);
  short8 a1 = *(const short8*)(rp + hb + (size_t)row * 64 + 32 + ko);
  f32x4 acc[4];
#pragma unroll
  for (int c = 0; c < 4; ++c) acc[c] = {0.f, 0.f, 0.f, 0.f};
  int s0 = dir ? it : 0;
  int nph = dir ? 16 - it : it + 1;
  SReg sr, nx;
  sload<64, 1024>(kp + hb + (size_t)s0 * 4096, vp + hb + s0 * 64, sr);
  swrite(Kt[0], Vt[0], sr);
  __syncthreads();
  for (int p = 0; p < nph; ++p) {
    int s = s0 + p;
    int cur = p & 1;
    if (p < nph - 1)
      sload<64, 1024>(kp + hb + (size_t)(s + 1) * 4096, vp + hb + (s + 1) * 64, nx);
    f32x4 sv[4];
    smm(a0, a1, Kt[cur], sv, lane);
    if (s == it) {
      if (dir) store_S<2>(sv, St, lane, w);
      else store_S<3>(sv, St, lane, w);
    } else {
      store_S<0>(sv, St, lane, w);
    }
    pv(St, Vt[cur], acc, lane, w);
    if (p < nph - 1) swrite(Kt[cur ^ 1], Vt[cur ^ 1], nx);
    __syncthreads();
  }
  float* y = dir ? yb : yf;
#pragma unroll
  for (int cf = 0; cf < 4; ++cf) {
    int c = cf * 16 + (lane & 15);
#pragma unroll
    for (int r = 0; r < 4; ++r) {
      int i = iw + (lane >> 4) * 4 + r;
      y[hb + (size_t)i * 64 + c] = acc[cf][r];
    }
  }
}

// ---------------- K8: GroupNorm over yf+yb, * ln + bias, * g(bf16) -> bf16 ----------------
__global__ __launch_bounds__(256)
void k8_gn2(const float* __restrict__ yf, const float* __restrict__ yb,
            const u16* __restrict__ g, const float* __restrict__ lnw,
            const float* __restrict__ lnb, u16* __restrict__ outb) {
  int bt = blockIdx.x;
  int b = bt >> 10, t = bt & 1023;
  int wv = threadIdx.x >> 6, lane = threadIdx.x & 63;
  for (int h = wv; h < HH; h += 4) {
    size_t idx = (((size_t)(b * HH + h)) * TT + t) * KK + lane;
    float v = yf[idx] + yb[idx];
    float s1 = v, s2 = v * v;
#pragma unroll
    for (int off = 32; off > 0; off >>= 1) {
      s1 += __shfl_xor(s1, off);
      s2 += __shfl_xor(s2, off);
    }
    float mu = s1 * (1.f / 64.f);
    float var = s2 * (1.f / 64.f) - mu * mu;
    float xn = (v - mu) * rsqrtf(var + 6.4e-4f);
    int d = h * 64 + lane;
    float o = xn * lnw[d] + lnb[d];
    outb[(size_t)bt * DD + d] = f2bf(o * bf2f(g[(size_t)bt * DD + d]));
  }
}

extern "C" void kernel_launch(void* const* d_in, const int* in_sizes, int n_in,
                              void* d_out, int out_size, void* d_ws, size_t ws_size,
                              hipStream_t stream) {
  const float* x      = (const float*)d_in[0];
  const float* maa_x  = (const float*)d_in[1];
  const float* maa_w  = (const float*)d_in[2];
  const float* maa_k  = (const float*)d_in[3];
  const float* maa_v  = (const float*)d_in[4];
  const float* maa_r  = (const float*)d_in[5];
  const float* maa_g  = (const float*)d_in[6];
  const float* maa_a  = (const float*)d_in[7];
  const float* w1mix  = (const float*)d_in[8];
  const float* w2mix  = (const float*)d_in[9];
  const float* tdecay = (const float*)d_in[10];
  const float* wdec1  = (const float*)d_in[11];
  const float* wdec2  = (const float*)d_in[12];
  const float* a0     = (const float*)d_in[13];
  const float* a1     = (const float*)d_in[14];
  const float* a2     = (const float*)d_in[15];
  const float* k_k    = (const float*)d_in[16];
  const float* k_a    = (const float*)d_in[17];
  const float* W_r    = (const float*)d_in[18];
  const float* W_k    = (const float*)d_in[19];
  const float* W_v    = (const float*)d_in[20];
  const float* W_g    = (const float*)d_in[21];
  const float* W_o    = (const float*)d_in[22];
  const float* lnw    = (const float*)d_in[23];
  const float* lnb    = (const float*)d_in[24];
  float* out = (float*)d_out;

  const size_t NEf = NE;
  float* F = (float*)d_ws;
  u16*   xxx_b  = (u16*)F;         // 2048x1024 bf16
  u16*   xw_b   = (u16*)(F + 1 * NEf);  // bf16; slot later reused: rfb/rbb
  u16*   xa_b   = (u16*)(F + 2 * NEf);  // bf16; slot later reused: kfb/kbw
  float* csfb   = F + 3 * NEf;
  float* csbsb  = F + 4 * NEf;
  float* P3     = F + 3 * NEf;     // consumed by reduce8b before csfb written
  float* PpartW = F + 3 * NEf;     // dead before gemm_k2b writes csfb
  float* PpartA = F + 4 * NEf;     // dead before k4k5 writes csbsb
  float* yf     = F + 3 * NEf;     // csfb dead after k4k5; k7 partial fwd
  float* yb     = F + 4 * NEf;     // csbsb dead after k6 (k5c consumed); k7 partial bwd
  float* iclr   = F + 5 * NEf;
  u16*   gb     = (u16*)(F + 6 * NEf);            // gate bf16
  u16*   hmixb  = (u16*)(F + 7 * NEf);            // 2048x192 bf16
  u16*   hdec_b = (u16*)(F + 7 * NEf + 524288);   // 2048x64 bf16
  u16*   ha_b   = (u16*)(F + 7 * NEf + 786432);   // 2048x64 bf16
  float* partb  = F + 7 * NEf + 917504;           // 32768 floats
  u16*   W1t    = (u16*)(F + 7 * NEf + 1048576);  // 192x1024 bf16
  u16*   wdec2t = (u16*)(F + 7 * NEf + 1146880);  // 1024x64 bf16
  u16*   a2t    = (u16*)(F + 7 * NEf + 1179648);  // 1024x64 bf16
  u16*   wdec1t = (u16*)(F + 7 * NEf + 1212416);  // 64x1024 bf16
  u16*   a1t    = (u16*)(F + 7 * NEf + 1245184);  // 64x1024 bf16
  u16*   W2t    = (u16*)(F + 7 * NEf + 1966080);  // 6x1024x32 bf16 (ends < 8*NE)
  u16* rfb = (u16*)xw_b;
  u16* rbb = rfb + NEf;
  u16* kfb = (u16*)xa_b;
  u16* kbw = kfb + NEf;
  u16* U = (u16*)(F + 8 * NEf);
  u16* xr_b = U + 0 * NEf;
  u16* xk_b = U + 1 * NEf;
  u16* xv_b = U + 2 * NEf;
  u16* xg_b = U + 3 * NEf;
  u16* rbuf = U + 4 * NEf;
  u16* kbuf = U + 5 * NEf;
  u16* vT   = U + 6 * NEf;
  u16* kkb  = U + 7 * NEf;
  u16* kkib = U + 8 * NEf;
  u16* vfT  = U + 9 * NEf;
  u16* vbT  = U + 10 * NEf;
  u16* gnb  = U + 11 * NEf;
  u16* WtR  = U + 12 * NEf;
  u16* WtK  = U + 12 * NEf + 1048576;
  u16* WtV  = U + 12 * NEf + 2097152;
  u16* WtG  = U + 12 * NEf + 3145728;
  u16* WtO  = U + 12 * NEf + 4194304;

  dim3 blk(256);

  pre<<<2256, blk, 0, stream>>>(w2mix, W2t, w1mix, W1t, wdec2, a2, wdec2t, a2t,
                                wdec1, a1, wdec1t, a1t, x, maa_x, xxx_b);

  hmix_g<<<1664, blk, 0, stream>>>(W_r, W_k, W_v, W_g, W_o,
                                   WtR, WtK, WtV, WtG, WtO,
                                   xxx_b, W1t, P3);
  reduce8b<<<1536, blk, 0, stream>>>(P3, hmixb, 393216);

  mixg<<<dim3(8, 16, 6), blk, 0, stream>>>(hmixb, W2t, x,
                                           maa_w, maa_k, maa_v, maa_r, maa_g, maa_a,
                                           xw_b, xa_b, xk_b, xv_b, xr_b, xg_b);

  gemm_bf4<<<1280, blk, 0, stream>>>(xr_b, xk_b, xv_b, xg_b,
                                     WtR, WtK, WtV, WtG,
                                     rbuf, kbuf, vT, gb,
                                     xw_b, wdec1t, PpartW, xa_b, a1t, PpartA);

  reduce8_pairb<<<dim3(512, 2), blk, 0, stream>>>(PpartW, PpartA, hdec_b, ha_b);
  gemm_k2b<<<dim3(16, 16, 2), blk, 0, stream>>>(hdec_b, wdec2t, csfb, tdecay,
                                                ha_b, a2t, iclr, a0);

  k4k5<<<8320, blk, 0, stream>>>(kbuf, kkb, kkib, iclr, k_k, k_a,
                                 csfb, csbsb, partb);

  // k6: 512 fwd + 512 bwd + 128 k5c = 1152 blocks (4 blocks/CU)
  k6_pass1<<<1152, blk, 0, stream>>>(kkb, kkib, vT, vfT, vbT,
                                     csbsb, partb, rbuf, kbuf,
                                     rfb, rbb, kfb, kbw);
  // k7: 512 fwd + 512 bwd = 1024 blocks -> yf/yb partials
  k7_pass2<<<1024, blk, 0, stream>>>(rfb, rbb, kfb, kbw, vfT, vbT, yf, yb);
  k8_gn2<<<NBT, blk, 0, stream>>>(yf, yb, gb, lnw, lnb, gnb);
  gemm_bfo<<<256, blk, 0, stream>>>(gnb, WtO, out);
}

// Round 21
// 170.152 us; speedup vs baseline: 1.0497x; 1.0497x over previous
//
#include <hip/hip_runtime.h>
#include <math.h>

#define BB 2
#define TT 1024
#define DD 1024
#define HH 16
#define KK 64
#define NBT 2048              // B*T
#define NE  2097152ULL        // B*T*D

typedef unsigned short u16;
typedef __attribute__((ext_vector_type(8))) short short8;   // 8 bf16 (4 VGPR)
typedef __attribute__((ext_vector_type(4))) short short4v;  // 4 bf16 (8B)
typedef __attribute__((ext_vector_type(4))) float f32x4;

__device__ __forceinline__ float bf2f(u16 u) {
  union { unsigned int i; float f; } v; v.i = ((unsigned int)u) << 16; return v.f;
}
__device__ __forceinline__ u16 f2bf(float x) {
  union { float f; unsigned int u; } v; v.f = x;
  unsigned int r = v.u + 0x7fffu + ((v.u >> 16) & 1u);
  return (u16)(r >> 16);
}
__device__ __forceinline__ f32x4 MFMA(short8 a, short8 b, f32x4 c) {
  return __builtin_amdgcn_mfma_f32_16x16x32_bf16(a, b, c, 0, 0, 0);
}
// XOR swizzle for [64 rows][128B] LDS tiles (G4: 128B rows are 32-way conflict)
__device__ __forceinline__ int swzb(int row, int kbyte) {
  return row * 128 + (kbyte ^ ((row & 7) << 4));
}
__device__ __forceinline__ void gload16(const void* g, void* l) {
  __builtin_amdgcn_global_load_lds((const __attribute__((address_space(1))) void*)g,
                                   (__attribute__((address_space(3))) void*)l, 16, 0, 0);
}

// ---------------- pre: small transposes + k1_xxx (flat grid 2256) ----------------
__global__ __launch_bounds__(256)
void pre(const float* __restrict__ W2, u16* __restrict__ W2t,
         const float* __restrict__ W1, u16* __restrict__ W1t,
         const float* __restrict__ wdec2, const float* __restrict__ a2,
         u16* __restrict__ wdec2t, u16* __restrict__ a2t,
         const float* __restrict__ wdec1, const float* __restrict__ a1,
         u16* __restrict__ wdec1t, u16* __restrict__ a1t,
         const float* __restrict__ x, const float* __restrict__ maa_x,
         u16* __restrict__ xxx_b) {
  __shared__ float tl[64][65];
  int idx = blockIdx.x;
  int tid = threadIdx.x;
  if (idx < 96) {
    int s = idx >> 4, d0 = (idx & 15) * 64;
    int c = tid & 63, r0 = (tid >> 6) * 8;
#pragma unroll
    for (int j = 0; j < 8; ++j)
      tl[r0 + j][c] = W2[(size_t)(s * 32 + r0 + j) * 1024 + d0 + c];
    __syncthreads();
    int d = tid >> 2, ms = (tid & 3) * 8;
    u16 o[8];
#pragma unroll
    for (int j = 0; j < 8; ++j) o[j] = f2bf(tl[ms + j][d]);
    *(short8*)(W2t + ((size_t)s * 1024 + d0 + d) * 32 + ms) = *(short8*)o;
  } else if (idx < 144) {
    int i = idx - 96;
    int k0 = (i & 15) * 64, n0 = (i >> 4) * 64;
    int r = tid >> 2, c0 = (tid & 3) * 16;
#pragma unroll
    for (int j = 0; j < 16; j += 4) {
      f32x4 v = *(const f32x4*)(W1 + (size_t)(k0 + r) * 192 + n0 + c0 + j);
      tl[r][c0 + j + 0] = v[0]; tl[r][c0 + j + 1] = v[1];
      tl[r][c0 + j + 2] = v[2]; tl[r][c0 + j + 3] = v[3];
    }
    __syncthreads();
    u16 o[16];
#pragma unroll
    for (int j = 0; j < 16; ++j) o[j] = f2bf(tl[c0 + j][r]);
    *(short8*)(W1t + (size_t)(n0 + r) * 1024 + k0 + c0) = *(short8*)(o);
    *(short8*)(W1t + (size_t)(n0 + r) * 1024 + k0 + c0 + 8) = *(short8*)(o + 8);
  } else if (idx < 176) {
    int i = idx - 144;
    int zz = i >> 4;
    const float* W = zz ? a2 : wdec2;
    u16* Wt = zz ? a2t : wdec2t;
    int n0 = (i & 15) * 64;
    int r = tid >> 2, c0 = (tid & 3) * 16;
#pragma unroll
    for (int j = 0; j < 16; j += 4) {
      f32x4 v = *(const f32x4*)(W + (size_t)r * 1024 + n0 + c0 + j);
      tl[r][c0 + j + 0] = v[0]; tl[r][c0 + j + 1] = v[1];
      tl[r][c0 + j + 2] = v[2]; tl[r][c0 + j + 3] = v[3];
    }
    __syncthreads();
    u16 o[16];
#pragma unroll
    for (int j = 0; j < 16; ++j) o[j] = f2bf(tl[c0 + j][r]);
    *(short8*)(Wt + (size_t)(n0 + r) * 64 + c0) = *(short8*)(o);
    *(short8*)(Wt + (size_t)(n0 + r) * 64 + c0 + 8) = *(short8*)(o + 8);
  } else if (idx < 208) {
    int i = idx - 176;
    int zz = i >> 4;
    const float* W = zz ? a1 : wdec1;
    u16* Wt = zz ? a1t : wdec1t;
    int k0 = (i & 15) * 64;
    int r = tid >> 2, c0 = (tid & 3) * 16;
#pragma unroll
    for (int j = 0; j < 16; j += 4) {
      f32x4 v = *(const f32x4*)(W + (size_t)(k0 + r) * 64 + c0 + j);
      tl[r][c0 + j + 0] = v[0]; tl[r][c0 + j + 1] = v[1];
      tl[r][c0 + j + 2] = v[2]; tl[r][c0 + j + 3] = v[3];
    }
    __syncthreads();
    u16 o[16];
#pragma unroll
    for (int j = 0; j < 16; ++j) o[j] = f2bf(tl[c0 + j][r]);
    *(short8*)(Wt + (size_t)r * 1024 + k0 + c0) = *(short8*)(o);
    *(short8*)(Wt + (size_t)r * 1024 + k0 + c0 + 8) = *(short8*)(o + 8);
  } else {
    int row = idx - 208;
    int t = row & (TT - 1);
    int d0 = tid * 4;
    size_t g = (size_t)row * DD + d0;
    f32x4 xc = *(const f32x4*)(x + g);
    f32x4 xl = {0.f, 0.f, 0.f, 0.f}, xr = {0.f, 0.f, 0.f, 0.f};
    if (t != 0) xl = *(const f32x4*)(x + g - DD);
    if (t != TT - 1) xr = *(const f32x4*)(x + g + DD);
    f32x4 mx = *(const f32x4*)(maa_x + d0);
    u16 o[4];
#pragma unroll
    for (int j = 0; j < 4; ++j)
      o[j] = f2bf(xc[j] + (0.5f * (xl[j] + xr[j]) - xc[j]) * mx[j]);
    *(short4v*)(xxx_b + g) = *(short4v*)o;
  }
}

// ---------------- hmix_g fused with big-5 W transposes (flat grid 1664) ----------------
__global__ __launch_bounds__(256)
void hmix_g(const float* __restrict__ W_r, const float* __restrict__ W_k,
            const float* __restrict__ W_v, const float* __restrict__ W_g,
            const float* __restrict__ W_o,
            u16* __restrict__ TR, u16* __restrict__ TK, u16* __restrict__ TV,
            u16* __restrict__ TG, u16* __restrict__ TO,
            const u16* __restrict__ xxx_b, const u16* __restrict__ W1t,
            float* __restrict__ P3) {
  __shared__ float tl[64][65];
  __shared__ u16 As[4096];  // 128x32
  __shared__ u16 Bs[2048];  // 64x32
  int idx = blockIdx.x;
  int tid = threadIdx.x;
  if (idx < 1280) {
    int z = idx >> 8, rem = idx & 255;
    const float* W = (z == 0) ? W_r : (z == 1) ? W_k : (z == 2) ? W_v : (z == 3) ? W_g : W_o;
    u16* Wt = (z == 0) ? TR : (z == 1) ? TK : (z == 2) ? TV : (z == 3) ? TG : TO;
    int k0 = (rem & 15) * 64, n0 = (rem >> 4) * 64;
    int r = tid >> 2, c0 = (tid & 3) * 16;
#pragma unroll
    for (int j = 0; j < 16; j += 4) {
      f32x4 v = *(const f32x4*)(W + (size_t)(k0 + r) * 1024 + n0 + c0 + j);
      tl[r][c0 + j + 0] = v[0]; tl[r][c0 + j + 1] = v[1];
      tl[r][c0 + j + 2] = v[2]; tl[r][c0 + j + 3] = v[3];
    }
    __syncthreads();
    u16 o[16];
#pragma unroll
    for (int j = 0; j < 16; ++j) o[j] = f2bf(tl[c0 + j][r]);
    *(short8*)(Wt + (size_t)(n0 + r) * 1024 + k0 + c0) = *(short8*)(o);
    *(short8*)(Wt + (size_t)(n0 + r) * 1024 + k0 + c0 + 8) = *(short8*)(o + 8);
    return;
  }
  int i = idx - 1280;                 // 0..383
  int n0 = (i % 3) * 64;
  int q = i / 3;                      // 0..127
  int m0 = (q & 15) * 128;
  int kb = q >> 4;                    // 0..7
  int w = tid >> 6, lane = tid & 63;
  int mq = w >> 1, nq = w & 1;
  f32x4 acc[4][2];
#pragma unroll
  for (int ii = 0; ii < 4; ++ii)
#pragma unroll
    for (int j = 0; j < 2; ++j) acc[ii][j] = {0.f, 0.f, 0.f, 0.f};
  for (int t = 0; t < 4; ++t) {
    int k0 = kb * 128 + t * 32;
#pragma unroll
    for (int c2 = 0; c2 < 2; ++c2) {
      int ch = w * 2 + c2;
      int row = ch * 16 + (lane >> 2);
      gload16(xxx_b + (size_t)(m0 + row) * 1024 + k0 + (lane & 3) * 8, As + ch * 512);
    }
    {
      int row = w * 16 + (lane >> 2);
      gload16(W1t + (size_t)(n0 + row) * 1024 + k0 + (lane & 3) * 8, Bs + w * 512);
    }
    __syncthreads();
    short8 a[4], b[2];
#pragma unroll
    for (int mf = 0; mf < 4; ++mf)
      a[mf] = *(const short8*)(As + (mq * 64 + mf * 16 + (lane & 15)) * 32 + (lane >> 4) * 8);
#pragma unroll
    for (int nf = 0; nf < 2; ++nf)
      b[nf] = *(const short8*)(Bs + (nq * 32 + nf * 16 + (lane & 15)) * 32 + (lane >> 4) * 8);
#pragma unroll
    for (int mf = 0; mf < 4; ++mf)
#pragma unroll
      for (int nf = 0; nf < 2; ++nf) acc[mf][nf] = MFMA(a[mf], b[nf], acc[mf][nf]);
    __syncthreads();
  }
#pragma unroll
  for (int mf = 0; mf < 4; ++mf) {
#pragma unroll
    for (int nf = 0; nf < 2; ++nf) {
      int mb = m0 + mq * 64 + mf * 16 + (lane >> 4) * 4;
      int n = n0 + nq * 32 + nf * 16 + (lane & 15);
#pragma unroll
      for (int r = 0; r < 4; ++r)
        P3[(size_t)kb * 393216 + (size_t)(mb + r) * 192 + n] = acc[mf][nf][r];
    }
  }
}

// ---------------- reduce 8 partials -> tanh -> bf16 (hmix) ----------------
__global__ __launch_bounds__(256)
void reduce8b(const float* __restrict__ P, u16* __restrict__ C, int total) {
  size_t i = (size_t)blockIdx.x * 256 + threadIdx.x;
  float s = 0.f;
#pragma unroll
  for (int kb = 0; kb < 8; ++kb) s += P[(size_t)kb * total + i];
  C[i] = f2bf(tanhf(s));
}

// ---------------- fused pair reduce -> bf16 ----------------
__global__ __launch_bounds__(256)
void reduce8_pairb(const float* __restrict__ Pw, const float* __restrict__ Pa,
                   u16* __restrict__ hdec_b, u16* __restrict__ ha_b) {
  int z = blockIdx.y;
  size_t i = (size_t)blockIdx.x * 256 + threadIdx.x;
  const float* P = z ? Pa : Pw;
  float s = 0.f;
#pragma unroll
  for (int kb = 0; kb < 8; ++kb) s += P[(size_t)kb * 131072 + i];
  if (z) ha_b[i] = f2bf(s);
  else hdec_b[i] = f2bf(tanhf(s));
}

// ---------------- mixg v3: MFMA mix + LDS round-trip + coalesced bf16 epilogue ----------------
__global__ __launch_bounds__(256)
void mixg(const u16* __restrict__ hmixb, const u16* __restrict__ W2t,
          const float* __restrict__ x,
          const float* __restrict__ maa_w, const float* __restrict__ maa_k,
          const float* __restrict__ maa_v, const float* __restrict__ maa_r,
          const float* __restrict__ maa_g, const float* __restrict__ maa_a,
          u16* __restrict__ xw_b, u16* __restrict__ xa_b,
          u16* __restrict__ xk_b, u16* __restrict__ xv_b,
          u16* __restrict__ xr_b, u16* __restrict__ xg_b) {
  __shared__ u16 shm[16384];
  u16* As = shm;
  u16* Bs = shm + 4096;
  u16* mixt = shm;
  int s = blockIdx.z;
  int m0 = blockIdx.y * 128, n0 = blockIdx.x * 128;
  int tid = threadIdx.x, w = tid >> 6, lane = tid & 63;
  int mq = w >> 1, nq = w & 1;
#pragma unroll
  for (int c2 = 0; c2 < 2; ++c2) {
    int ch = w * 2 + c2;
    int row = ch * 16 + (lane >> 2);
    gload16(hmixb + (size_t)(m0 + row) * 192 + s * 32 + (lane & 3) * 8, As + ch * 512);
    gload16(W2t + ((size_t)s * 1024 + n0 + row) * 32 + (lane & 3) * 8, Bs + ch * 512);
  }
  __syncthreads();
  short8 a[4], b[4];
#pragma unroll
  for (int mf = 0; mf < 4; ++mf)
    a[mf] = *(const short8*)(As + (mq * 64 + mf * 16 + (lane & 15)) * 32 + (lane >> 4) * 8);
#pragma unroll
  for (int nf = 0; nf < 4; ++nf)
    b[nf] = *(const short8*)(Bs + (nq * 64 + nf * 16 + (lane & 15)) * 32 + (lane >> 4) * 8);
  f32x4 acc[4][4];
#pragma unroll
  for (int mf = 0; mf < 4; ++mf)
#pragma unroll
    for (int nf = 0; nf < 4; ++nf) {
      f32x4 z = {0.f, 0.f, 0.f, 0.f};
      acc[mf][nf] = MFMA(a[mf], b[nf], z);
    }
  __syncthreads();
#pragma unroll
  for (int mf = 0; mf < 4; ++mf) {
#pragma unroll
    for (int nf = 0; nf < 4; ++nf) {
      int col = nq * 64 + nf * 16 + (lane & 15);
#pragma unroll
      for (int r = 0; r < 4; ++r) {
        int row = mq * 64 + mf * 16 + (lane >> 4) * 4 + r;
        mixt[row * 128 + col] = f2bf(acc[mf][nf][r]);
      }
    }
  }
  __syncthreads();
  const float* maa = (s == 0) ? maa_w : (s == 1) ? maa_k : (s == 2) ? maa_v
                    : (s == 3) ? maa_r : (s == 4) ? maa_g : maa_a;
  u16* dst = (s == 0) ? xw_b : (s == 1) ? xk_b : (s == 2) ? xv_b
            : (s == 3) ? xr_b : (s == 4) ? xg_b : xa_b;
  int cg = tid & 15;
  int rowg = tid >> 4;
  int d0 = n0 + cg * 8;
  f32x4 ma0 = *(const f32x4*)(maa + d0);
  f32x4 ma1 = *(const f32x4*)(maa + d0 + 4);
#pragma unroll
  for (int rr = 0; rr < 8; ++rr) {
    int row = rr * 16 + rowg;
    int m = m0 + row;
    int t = m & (TT - 1);
    size_t g = (size_t)m * DD + d0;
    f32x4 xc0 = *(const f32x4*)(x + g);
    f32x4 xc1 = *(const f32x4*)(x + g + 4);
    f32x4 xl0 = {0.f, 0.f, 0.f, 0.f}, xl1 = {0.f, 0.f, 0.f, 0.f};
    f32x4 xr0 = {0.f, 0.f, 0.f, 0.f}, xr1 = {0.f, 0.f, 0.f, 0.f};
    if (t != 0) { xl0 = *(const f32x4*)(x + g - DD); xl1 = *(const f32x4*)(x + g - DD + 4); }
    if (t != TT - 1) { xr0 = *(const f32x4*)(x + g + DD); xr1 = *(const f32x4*)(x + g + DD + 4); }
    short8 mv = *(const short8*)(mixt + row * 128 + cg * 8);
    u16 o[8];
#pragma unroll
    for (int j = 0; j < 8; ++j) {
      float xcj = (j < 4) ? xc0[j & 3] : xc1[j & 3];
      float xlj = (j < 4) ? xl0[j & 3] : xl1[j & 3];
      float xrj = (j < 4) ? xr0[j & 3] : xr1[j & 3];
      float maj = (j < 4) ? ma0[j & 3] : ma1[j & 3];
      float dx = 0.5f * (xlj + xrj) - xcj;
      o[j] = f2bf(xcj + dx * (maj + bf2f((u16)mv[j])));
    }
    *(short8*)(dst + g) = *(short8*)o;
  }
}

// ---------------- fused 4-way bf16 MFMA projection GEMM + skinny LoRA-down ----------------
__global__ __launch_bounds__(256)
void gemm_bf4(const u16* __restrict__ xr, const u16* __restrict__ xk,
              const u16* __restrict__ xv, const u16* __restrict__ xg,
              const u16* __restrict__ WtR, const u16* __restrict__ WtK,
              const u16* __restrict__ WtV, const u16* __restrict__ WtG,
              u16* __restrict__ rbuf, u16* __restrict__ kbuf,
              u16* __restrict__ vT, u16* __restrict__ gb,
              const u16* __restrict__ xw_b, const u16* __restrict__ wdec1t,
              float* __restrict__ PpartW,
              const u16* __restrict__ xa_b, const u16* __restrict__ a1t,
              float* __restrict__ PpartA) {
  __shared__ u16 As[2][4096];
  __shared__ u16 Bs[2][2048];
  int wgid = blockIdx.x;
  int tid = threadIdx.x, w = tid >> 6, lane = tid & 63;
  int mq = w >> 1, nq = w & 1;
  if (wgid >= 1024) {
    int i = wgid - 1024;
    int m0 = (i & 15) * 128;
    int kb = (i >> 4) & 7;
    int z = i >> 7;
    const u16* A = z ? xa_b : xw_b;
    const u16* Bt = z ? a1t : wdec1t;
    float* P = z ? PpartA : PpartW;
    f32x4 acc[4][2];
#pragma unroll
    for (int ii = 0; ii < 4; ++ii)
#pragma unroll
      for (int j = 0; j < 2; ++j) acc[ii][j] = {0.f, 0.f, 0.f, 0.f};
    for (int t = 0; t < 4; ++t) {
      int k0 = kb * 128 + t * 32;
#pragma unroll
      for (int c2 = 0; c2 < 2; ++c2) {
        int ch = w * 2 + c2;
        int row = ch * 16 + (lane >> 2);
        gload16(A + (size_t)(m0 + row) * 1024 + k0 + (lane & 3) * 8, As[0] + ch * 512);
      }
      {
        int row = w * 16 + (lane >> 2);
        gload16(Bt + (size_t)row * 1024 + k0 + (lane & 3) * 8, Bs[0] + w * 512);
      }
      __syncthreads();
      short8 a[4], b[2];
#pragma unroll
      for (int mf = 0; mf < 4; ++mf)
        a[mf] = *(const short8*)(As[0] + (mq * 64 + mf * 16 + (lane & 15)) * 32 + (lane >> 4) * 8);
#pragma unroll
      for (int nf = 0; nf < 2; ++nf)
        b[nf] = *(const short8*)(Bs[0] + (nq * 32 + nf * 16 + (lane & 15)) * 32 + (lane >> 4) * 8);
#pragma unroll
      for (int mf = 0; mf < 4; ++mf)
#pragma unroll
        for (int nf = 0; nf < 2; ++nf) acc[mf][nf] = MFMA(a[mf], b[nf], acc[mf][nf]);
      __syncthreads();
    }
#pragma unroll
    for (int mf = 0; mf < 4; ++mf) {
#pragma unroll
      for (int nf = 0; nf < 2; ++nf) {
        int mb = m0 + mq * 64 + mf * 16 + (lane >> 4) * 4;
        int n = nq * 32 + nf * 16 + (lane & 15);
#pragma unroll
        for (int r = 0; r < 4; ++r)
          P[(size_t)kb * 131072 + (size_t)(mb + r) * 64 + n] = acc[mf][nf][r];
      }
    }
    return;
  }
  int xcd = wgid & 7, idx = wgid >> 3;
  int z = xcd >> 1, mhalf = xcd & 1;
  int mloc = idx & 7, nt = idx >> 3;
  int m0 = (mhalf * 8 + mloc) * 128;
  int n0 = nt * 64;
  const u16* A = (z == 0) ? xr : (z == 1) ? xk : (z == 2) ? xv : xg;
  const u16* Bt = (z == 0) ? WtR : (z == 1) ? WtK : (z == 2) ? WtV : WtG;
  int arow0 = (w * 2) * 16 + (lane >> 2);
  int arow1 = (w * 2 + 1) * 16 + (lane >> 2);
  int brow = w * 16 + (lane >> 2);
  int kc = (lane & 3) * 8;
  f32x4 acc[4][2];
#pragma unroll
  for (int i = 0; i < 4; ++i)
#pragma unroll
    for (int j = 0; j < 2; ++j) acc[i][j] = {0.f, 0.f, 0.f, 0.f};
  gload16(A + (size_t)(m0 + arow0) * 1024 + kc, As[0] + (w * 2) * 512);
  gload16(A + (size_t)(m0 + arow1) * 1024 + kc, As[0] + (w * 2 + 1) * 512);
  gload16(Bt + (size_t)(n0 + brow) * 1024 + kc, Bs[0] + w * 512);
  __syncthreads();
  for (int t = 0; t < 32; ++t) {
    int cur = t & 1;
    if (t < 31) {
      int kn = (t + 1) * 32;
      gload16(A + (size_t)(m0 + arow0) * 1024 + kn + kc, As[cur ^ 1] + (w * 2) * 512);
      gload16(A + (size_t)(m0 + arow1) * 1024 + kn + kc, As[cur ^ 1] + (w * 2 + 1) * 512);
      gload16(Bt + (size_t)(n0 + brow) * 1024 + kn + kc, Bs[cur ^ 1] + w * 512);
    }
    short8 a[4], b[2];
#pragma unroll
    for (int mf = 0; mf < 4; ++mf)
      a[mf] = *(const short8*)(As[cur] + (mq * 64 + mf * 16 + (lane & 15)) * 32 + (lane >> 4) * 8);
#pragma unroll
    for (int nf = 0; nf < 2; ++nf)
      b[nf] = *(const short8*)(Bs[cur] + (nq * 32 + nf * 16 + (lane & 15)) * 32 + (lane >> 4) * 8);
#pragma unroll
    for (int mf = 0; mf < 4; ++mf)
#pragma unroll
      for (int nf = 0; nf < 2; ++nf) acc[mf][nf] = MFMA(a[mf], b[nf], acc[mf][nf]);
    __syncthreads();
  }
#pragma unroll
  for (int mf = 0; mf < 4; ++mf) {
#pragma unroll
    for (int nf = 0; nf < 2; ++nf) {
      int mb = m0 + mq * 64 + mf * 16 + (lane >> 4) * 4;
      int n = n0 + nq * 32 + nf * 16 + (lane & 15);
      if (z == 2) {  // VTB: vT[b*H+h][k][t] bf16
        u16 o[4];
#pragma unroll
        for (int r = 0; r < 4; ++r) o[r] = f2bf(acc[mf][nf][r]);
        int b2 = mb >> 10, t = mb & 1023;
        *(short4v*)(vT + (((size_t)(b2 * HH + (n >> 6))) * KK + (n & 63)) * TT + t) = *(short4v*)o;
      } else if (z == 3) {  // gate: silu -> bf16 flat
#pragma unroll
        for (int r = 0; r < 4; ++r) {
          int m = mb + r;
          float v = acc[mf][nf][r];
          gb[(size_t)m * 1024 + n] = f2bf(v / (1.f + __expf(-v)));
        }
      } else {  // HEADB bf16 head layout
        u16* C = (z == 0) ? rbuf : kbuf;
#pragma unroll
        for (int r = 0; r < 4; ++r) {
          int m = mb + r;
          int b2 = m >> 10, t = m & 1023;
          C[(((size_t)(b2 * HH + (n >> 6))) * TT + t) * KK + (n & 63)] = f2bf(acc[mf][nf][r]);
        }
      }
    }
  }
}

// ---------------- W_o bf16 MFMA GEMM (128x64, BK=32 dbuf, XCD-partitioned 256 blocks) ----------------
__global__ __launch_bounds__(256)
void gemm_bfo(const u16* __restrict__ A, const u16* __restrict__ Bt,
              float* __restrict__ C) {
  __shared__ u16 As[2][4096];
  __shared__ u16 Bs[2][2048];
  int wgid = blockIdx.x;
  int xcd = wgid & 7, idx = wgid >> 3;
  int mloc = idx & 1, nt = idx >> 1;
  int m0 = (xcd * 2 + mloc) * 128;
  int n0 = nt * 64;
  int tid = threadIdx.x, w = tid >> 6, lane = tid & 63;
  int mq = w >> 1, nq = w & 1;
  int arow0 = (w * 2) * 16 + (lane >> 2);
  int arow1 = (w * 2 + 1) * 16 + (lane >> 2);
  int brow = w * 16 + (lane >> 2);
  int kc = (lane & 3) * 8;
  f32x4 acc[4][2];
#pragma unroll
  for (int i = 0; i < 4; ++i)
#pragma unroll
    for (int j = 0; j < 2; ++j) acc[i][j] = {0.f, 0.f, 0.f, 0.f};
  gload16(A + (size_t)(m0 + arow0) * 1024 + kc, As[0] + (w * 2) * 512);
  gload16(A + (size_t)(m0 + arow1) * 1024 + kc, As[0] + (w * 2 + 1) * 512);
  gload16(Bt + (size_t)(n0 + brow) * 1024 + kc, Bs[0] + w * 512);
  __syncthreads();
  for (int t = 0; t < 32; ++t) {
    int cur = t & 1;
    if (t < 31) {
      int kn = (t + 1) * 32;
      gload16(A + (size_t)(m0 + arow0) * 1024 + kn + kc, As[cur ^ 1] + (w * 2) * 512);
      gload16(A + (size_t)(m0 + arow1) * 1024 + kn + kc, As[cur ^ 1] + (w * 2 + 1) * 512);
      gload16(Bt + (size_t)(n0 + brow) * 1024 + kn + kc, Bs[cur ^ 1] + w * 512);
    }
    short8 a[4], b[2];
#pragma unroll
    for (int mf = 0; mf < 4; ++mf)
      a[mf] = *(const short8*)(As[cur] + (mq * 64 + mf * 16 + (lane & 15)) * 32 + (lane >> 4) * 8);
#pragma unroll
    for (int nf = 0; nf < 2; ++nf)
      b[nf] = *(const short8*)(Bs[cur] + (nq * 32 + nf * 16 + (lane & 15)) * 32 + (lane >> 4) * 8);
#pragma unroll
    for (int mf = 0; mf < 4; ++mf)
#pragma unroll
      for (int nf = 0; nf < 2; ++nf) acc[mf][nf] = MFMA(a[mf], b[nf], acc[mf][nf]);
    __syncthreads();
  }
#pragma unroll
  for (int mf = 0; mf < 4; ++mf) {
#pragma unroll
    for (int nf = 0; nf < 2; ++nf) {
      int mb = m0 + mq * 64 + mf * 16 + (lane >> 4) * 4;
      int n = n0 + nq * 32 + nf * 16 + (lane & 15);
#pragma unroll
      for (int r = 0; r < 4; ++r)
        C[(size_t)(mb + r) * 1024 + n] = acc[mf][nf][r];
    }
  }
}

// ---------------- gemm_k2b: dual K=64 bf16 MFMA LoRA-up, fused k5a (z=0) + k4 (z=1) ----------------
// z=0: w = hdec@wdec2 + tdecay -> wh=-exp(w) -> csbs + per-chunk partials -> part
// z=1: iclr = sigmoid(ha@a2 + a0) in-reg -> kk-normalize -> kkb/kkib/kbuf update
__global__ __launch_bounds__(256)
void gemm_k2b(const u16* __restrict__ A0, const u16* __restrict__ B0t,
              const float* __restrict__ bias0,
              float* __restrict__ csbs, float* __restrict__ part,
              const u16* __restrict__ A1, const u16* __restrict__ B1t,
              const float* __restrict__ bias1,
              u16* __restrict__ kbuf, u16* __restrict__ kkb, u16* __restrict__ kkib,
              const float* __restrict__ k_k, const float* __restrict__ k_a) {
  __shared__ u16 As[8192];  // [2 ks][128 rows][32 k]
  __shared__ u16 Bs[4096];  // [2 ks][64 rows][32 k]
  __shared__ float hsum[128][2];
  int z = blockIdx.z;
  const u16* A = z ? A1 : A0;
  const u16* Bt = z ? B1t : B0t;
  const float* bias = z ? bias1 : bias0;
  int n0 = blockIdx.x * 64, m0 = blockIdx.y * 128;
  int tid = threadIdx.x, w = tid >> 6, lane = tid & 63;
  int mq = w >> 1, nq = w & 1;
#pragma unroll
  for (int j = 0; j < 4; ++j) {
    int q = w * 4 + j;
    int ks = q >> 3, rg = q & 7;
    int row = rg * 16 + (lane >> 2);
    int kc = ks * 32 + (lane & 3) * 8;
    gload16(A + (size_t)(m0 + row) * 64 + kc, As + q * 512);
  }
#pragma unroll
  for (int j = 0; j < 2; ++j) {
    int q = w * 2 + j;
    int ks = q >> 2, rg = q & 3;
    int row = rg * 16 + (lane >> 2);
    int kc = ks * 32 + (lane & 3) * 8;
    gload16(Bt + (size_t)(n0 + row) * 64 + kc, Bs + q * 512);
  }
  __syncthreads();
  f32x4 acc[4][2];
#pragma unroll
  for (int i = 0; i < 4; ++i)
#pragma unroll
    for (int j = 0; j < 2; ++j) acc[i][j] = {0.f, 0.f, 0.f, 0.f};
#pragma unroll
  for (int ks = 0; ks < 2; ++ks) {
    short8 a[4], b[2];
#pragma unroll
    for (int mf = 0; mf < 4; ++mf)
      a[mf] = *(const short8*)(As + ks * 4096 + (mq * 64 + mf * 16 + (lane & 15)) * 32 + (lane >> 4) * 8);
#pragma unroll
    for (int nf = 0; nf < 2; ++nf)
      b[nf] = *(const short8*)(Bs + ks * 2048 + (nq * 32 + nf * 16 + (lane & 15)) * 32 + (lane >> 4) * 8);
#pragma unroll
    for (int mf = 0; mf < 4; ++mf)
#pragma unroll
      for (int nf = 0; nf < 2; ++nf) acc[mf][nf] = MFMA(a[mf], b[nf], acc[mf][nf]);
  }
  int b2 = m0 >> 10, h = n0 >> 6;
  int bh = b2 * HH + h;
  int jj = lane & 15, g = lane >> 4;
  if (z == 0) {
    // k5a fused: wh = -exp(w) -> csbs; chunk partials -> part
    float psum[2] = {0.f, 0.f};
#pragma unroll
    for (int mf = 0; mf < 4; ++mf) {
      int mb = m0 + mq * 64 + mf * 16 + g * 4;
#pragma unroll
      for (int nf = 0; nf < 2; ++nf) {
        int n = n0 + nq * 32 + nf * 16 + jj;
        float bv = bias[n];
#pragma unroll
        for (int r = 0; r < 4; ++r) {
          int t = (mb + r) & 1023;
          float wh = -expf(acc[mf][nf][r] + bv);
          csbs[(((size_t)bh) * TT + t) * KK + (n & 63)] = wh;
          psum[nf] += wh;
        }
      }
    }
#pragma unroll
    for (int nf = 0; nf < 2; ++nf) {
      psum[nf] += __shfl_xor(psum[nf], 16);
      psum[nf] += __shfl_xor(psum[nf], 32);
    }
    if (lane < 16) {
      int c = ((m0 & 1023) >> 6) + mq;
#pragma unroll
      for (int nf = 0; nf < 2; ++nf)
        part[((size_t)bh * 16 + c) * 64 + nq * 32 + nf * 16 + jj] = psum[nf];
    }
  } else {
    // k4 fused: iclr in-reg; kk-normalize over K=64 per row
    float kk2[2], ka2[2], icv[4][2][4], kvf[4][2][4];
#pragma unroll
    for (int nf = 0; nf < 2; ++nf) {
      int n = n0 + nq * 32 + nf * 16 + jj;
      kk2[nf] = k_k[n];
      ka2[nf] = k_a[n];
    }
#pragma unroll
    for (int mf = 0; mf < 4; ++mf) {
      int mb = m0 + mq * 64 + mf * 16 + g * 4;
#pragma unroll
      for (int nf = 0; nf < 2; ++nf) {
        int n = n0 + nq * 32 + nf * 16 + jj;
        float bv = bias[n];
#pragma unroll
        for (int r = 0; r < 4; ++r) {
          int t = (mb + r) & 1023;
          size_t gidx = (((size_t)bh) * TT + t) * KK + (n & 63);
          icv[mf][nf][r] = 1.f / (1.f + expf(-(acc[mf][nf][r] + bv)));
          kvf[mf][nf][r] = bf2f(kbuf[gidx]);
        }
      }
    }
#pragma unroll
    for (int mf = 0; mf < 4; ++mf) {
#pragma unroll
      for (int r = 0; r < 4; ++r) {
        float s = 0.f;
#pragma unroll
        for (int nf = 0; nf < 2; ++nf) {
          float kkh = kvf[mf][nf][r] * kk2[nf];
          s += kkh * kkh;
        }
        s += __shfl_xor(s, 1);
        s += __shfl_xor(s, 2);
        s += __shfl_xor(s, 4);
        s += __shfl_xor(s, 8);
        if (jj == 0) hsum[mq * 64 + mf * 16 + g * 4 + r][nq] = s;
      }
    }
    __syncthreads();
#pragma unroll
    for (int mf = 0; mf < 4; ++mf) {
      int mb = m0 + mq * 64 + mf * 16 + g * 4;
#pragma unroll
      for (int r = 0; r < 4; ++r) {
        int rl = mq * 64 + mf * 16 + g * 4 + r;
        float ss = hsum[rl][0] + hsum[rl][1];
        float nrm = fmaxf(sqrtf(ss), 1e-12f);
        int t = (mb + r) & 1023;
#pragma unroll
        for (int nf = 0; nf < 2; ++nf) {
          int n = n0 + nq * 32 + nf * 16 + jj;
          size_t gidx = (((size_t)bh) * TT + t) * KK + (n & 63);
          float kkh = kvf[mf][nf][r] * kk2[nf];
          float kkv = kkh / nrm;
          float ic = icv[mf][nf][r];
          kkb[gidx] = f2bf(kkv);
          kkib[gidx] = f2bf(kkv * ic);
          kbuf[gidx] = f2bf(kvf[mf][nf][r] * (1.f + (ic - 1.f) * ka2[nf]));
        }
      }
    }
  }
}

// ---------------- attention tile helpers (bf16 MFMA, T5 setprio on MFMA clusters) ----------------
struct SReg { short8 a0, a1, b0, b1; };
template <int RSA, int RSB>
__device__ __forceinline__ void sload(const u16* ka, const u16* vb, SReg& r) {
  int t0 = threadIdx.x, t1 = threadIdx.x + 256;
  r.a0 = *(const short8*)(ka + (size_t)(t0 >> 3) * RSA + (t0 & 7) * 8);
  r.a1 = *(const short8*)(ka + (size_t)(t1 >> 3) * RSA + (t1 & 7) * 8);
  r.b0 = *(const short8*)(vb + (size_t)(t0 >> 3) * RSB + (t0 & 7) * 8);
  r.b1 = *(const short8*)(vb + (size_t)(t1 >> 3) * RSB + (t1 & 7) * 8);
}
__device__ __forceinline__ void swrite(u16* Kt, u16* Vt, const SReg& r) {
  int t0 = threadIdx.x, t1 = threadIdx.x + 256;
  *(short8*)((char*)Kt + swzb(t0 >> 3, (t0 & 7) * 16)) = r.a0;
  *(short8*)((char*)Kt + swzb(t1 >> 3, (t1 & 7) * 16)) = r.a1;
  *(short8*)((char*)Vt + swzb(t0 >> 3, (t0 & 7) * 16)) = r.b0;
  *(short8*)((char*)Vt + swzb(t1 >> 3, (t1 & 7) * 16)) = r.b1;
}
template <int MASK>  // 0 none, 1 jl<il, 2 jl>il, 3 jl<=il
__device__ __forceinline__ void store_S(const f32x4 s[4], u16* St, int lane, int w) {
  int ig0 = w * 16 + (lane >> 4) * 4;
#pragma unroll
  for (int jf = 0; jf < 4; ++jf) {
    int jl = jf * 16 + (lane & 15);
#pragma unroll
    for (int r = 0; r < 4; ++r) {
      int il = ig0 + r;
      float v = s[jf][r];
      if (MASK == 1 && !(jl < il)) v = 0.f;
      if (MASK == 2 && !(jl > il)) v = 0.f;
      if (MASK == 3 && !(jl <= il)) v = 0.f;
      *(u16*)((char*)St + swzb(il, jl * 2)) = f2bf(v);
    }
  }
}
__device__ __forceinline__ void smm(short8 a0, short8 a1, const u16* Kt, f32x4 s[4], int lane) {
  __builtin_amdgcn_s_setprio(1);
#pragma unroll
  for (int jf = 0; jf < 4; ++jf) {
    f32x4 z = {0.f, 0.f, 0.f, 0.f};
    short8 kb0 = *(const short8*)((const char*)Kt + swzb(jf * 16 + (lane & 15), (lane >> 4) * 16));
    z = MFMA(a0, kb0, z);
    short8 kb1 = *(const short8*)((const char*)Kt + swzb(jf * 16 + (lane & 15), 64 + (lane >> 4) * 16));
    z = MFMA(a1, kb1, z);
    s[jf] = z;
  }
  __builtin_amdgcn_s_setprio(0);
}
__device__ __forceinline__ void pv(const u16* St, const u16* Vt, f32x4 acc[4], int lane, int w) {
  __builtin_amdgcn_s_setprio(1);
#pragma unroll
  for (int ks = 0; ks < 2; ++ks) {
    short8 a = *(const short8*)((const char*)St + swzb(w * 16 + (lane & 15), ks * 64 + (lane >> 4) * 16));
#pragma unroll
    for (int cf = 0; cf < 4; ++cf) {
      short8 b = *(const short8*)((const char*)Vt + swzb(cf * 16 + (lane & 15), ks * 64 + (lane >> 4) * 16));
      acc[cf] = MFMA(a, b, acc[cf]);
    }
  }
  __builtin_amdgcn_s_setprio(0);
}

// ---------------- K6: pass 1, fwd/bwd split (wg<512 fwd, 512..1023 bwd, >=1024 k5c) ----------------
__global__ __launch_bounds__(256)
void k6_pass1(const u16* __restrict__ kk, const u16* __restrict__ kki,
              const u16* __restrict__ vT, u16* __restrict__ vfT, u16* __restrict__ vbT,
              const float* __restrict__ csbs, const float* __restrict__ part,
              const u16* __restrict__ rb, const u16* __restrict__ kb,
              u16* __restrict__ rfb, u16* __restrict__ rbb,
              u16* __restrict__ kfb, u16* __restrict__ kbw) {
  __shared__ u16 Kt[2][4096], Vt[2][4096], St[4096];
  int wg = blockIdx.x;
  int tid = threadIdx.x;
  if (wg >= 1024) {
    // k5c: prefix + cs recurrence + clip + factored operands
    int bc = (wg - 1024) * 4 + (tid >> 6);
    int bh = bc >> 4, c = bc & 15;
    int lane = tid & 63;
    size_t hb = (size_t)bh * TT * KK;
    float run = 0.f, csb512 = 0.f;
    for (int cc = 0; cc < 16; ++cc) {
      float pvv = part[((size_t)bh * 16 + cc) * 64 + lane];
      if (cc < c) run += pvv;
      if (cc < 8) csb512 += pvv;
    }
    float wh512 = csbs[hb + (size_t)512 * KK + lane];
    float cs512 = csb512 + wh512;
    size_t base = hb + (size_t)c * 64 * KK + lane;
    float cs = run;
    for (int i = 0; i < 64; ++i) {
      size_t g = base + (size_t)i * KK;
      float wh = csbs[g];
      cs += wh;
      float cf = fminf(fmaxf(cs - cs512, -60.f), 60.f);
      float cb = fminf(fmaxf((cs - wh) - csb512, -60.f), 60.f);
      float rvf = bf2f(rb[g]);
      float kvf = bf2f(kb[g]);
      rfb[g] = f2bf(rvf * __expf(cf));
      kfb[g] = f2bf(kvf * __expf(-cf));
      rbb[g] = f2bf(rvf * __expf(-cb));
      kbw[g] = f2bf(kvf * __expf(cb));
    }
    return;
  }
  int dir = (wg >= 512);
  int w0 = dir ? wg - 512 : wg;
  int bh = w0 & 31, it = w0 >> 5, i0 = it * 64;
  size_t hb = (size_t)bh * 65536;
  int w = tid >> 6, lane = tid & 63;
  int iw = i0 + w * 16;
  int row = iw + (lane & 15), ko = (lane >> 4) * 8;
  short8 a0 = *(const short8*)(kki + hb + (size_t)row * 64 + ko);
  short8 a1 = *(const short8*)(kki + hb + (size_t)row * 64 + 32 + ko);
  f32x4 acc[4];
#pragma unroll
  for (int c = 0; c < 4; ++c) acc[c] = {0.f, 0.f, 0.f, 0.f};
  int s0 = dir ? it : 0;
  int nph = dir ? 16 - it : it + 1;
  SReg sr, nx;
  sload<64, 1024>(kk + hb + (size_t)s0 * 4096, vT + hb + s0 * 64, sr);
  swrite(Kt[0], Vt[0], sr);
  __syncthreads();
  for (int p = 0; p < nph; ++p) {
    int s = s0 + p;
    int cur = p & 1;
    if (p < nph - 1)
      sload<64, 1024>(kk + hb + (size_t)(s + 1) * 4096, vT + hb + (s + 1) * 64, nx);
    f32x4 sv[4];
    smm(a0, a1, Kt[cur], sv, lane);
    if (s == it) {
      if (dir) store_S<2>(sv, St, lane, w);
      else store_S<1>(sv, St, lane, w);
    } else {
      store_S<0>(sv, St, lane, w);
    }
    pv(St, Vt[cur], acc, lane, w);
    if (p < nph - 1) swrite(Kt[cur ^ 1], Vt[cur ^ 1], nx);
    __syncthreads();
  }
  u16* dst = dir ? vbT : vfT;
#pragma unroll
  for (int cf = 0; cf < 4; ++cf) {
    int c = cf * 16 + (lane & 15);
    int i = iw + (lane >> 4) * 4;
    size_t g = hb + (size_t)c * 1024 + i;
    short4v vv = *(const short4v*)(vT + g);
    u16 o1[4];
#pragma unroll
    for (int r = 0; r < 4; ++r)
      o1[r] = f2bf(bf2f((u16)vv[r]) - acc[cf][r]);
    *(short4v*)(dst + g) = *(short4v*)o1;
  }
}

// ---------------- K7: pass 2, fwd/bwd split -> partial f32 outputs yf/yb ----------------
__global__ __launch_bounds__(256)
void k7_pass2(const u16* __restrict__ rfb, const u16* __restrict__ rbb,
              const u16* __restrict__ kfb, const u16* __restrict__ kbw,
              const u16* __restrict__ vfT, const u16* __restrict__ vbT,
              float* __restrict__ yf, float* __restrict__ yb) {
  __shared__ u16 Kt[2][4096], Vt[2][4096], St[4096];
  int wg = blockIdx.x;
  int dir = (wg >= 512);
  int w0 = dir ? wg - 512 : wg;
  int bh = w0 & 31, it = w0 >> 5, i0 = it * 64;
  size_t hb = (size_t)bh * 65536;
  int tid = threadIdx.x, w = tid >> 6, lane = tid & 63;
  int iw = i0 + w * 16;
  int row = iw + (lane & 15), ko = (lane >> 4) * 8;
  const u16* rp = dir ? rbb : rfb;
  const u16* kp = dir ? kbw : kfb;
  const u16* vp = dir ? vbT : vfT;
  short8 a0 = *(const short8*)(rp + hb + (size_t)row * 64 + ko);
  short8 a1 = *(const short8*)(rp + hb + (size_t)row * 64 + 32 + ko);
  f32x4 acc[4];
#pragma unroll
  for (int c = 0; c < 4; ++c) acc[c] = {0.f, 0.f, 0.f, 0.f};
  int s0 = dir ? it : 0;
  int nph = dir ? 16 - it : it + 1;
  SReg sr, nx;
  sload<64, 1024>(kp + hb + (size_t)s0 * 4096, vp + hb + s0 * 64, sr);
  swrite(Kt[0], Vt[0], sr);
  __syncthreads();
  for (int p = 0; p < nph; ++p) {
    int s = s0 + p;
    int cur = p & 1;
    if (p < nph - 1)
      sload<64, 1024>(kp + hb + (size_t)(s + 1) * 4096, vp + hb + (s + 1) * 64, nx);
    f32x4 sv[4];
    smm(a0, a1, Kt[cur], sv, lane);
    if (s == it) {
      if (dir) store_S<2>(sv, St, lane, w);
      else store_S<3>(sv, St, lane, w);
    } else {
      store_S<0>(sv, St, lane, w);
    }
    pv(St, Vt[cur], acc, lane, w);
    if (p < nph - 1) swrite(Kt[cur ^ 1], Vt[cur ^ 1], nx);
    __syncthreads();
  }
  float* y = dir ? yb : yf;
#pragma unroll
  for (int cf = 0; cf < 4; ++cf) {
    int c = cf * 16 + (lane & 15);
#pragma unroll
    for (int r = 0; r < 4; ++r) {
      int i = iw + (lane >> 4) * 4 + r;
      y[hb + (size_t)i * 64 + c] = acc[cf][r];
    }
  }
}

// ---------------- K8: GroupNorm over yf+yb, * ln + bias, * g(bf16) -> bf16 ----------------
__global__ __launch_bounds__(256)
void k8_gn2(const float* __restrict__ yf, const float* __restrict__ yb,
            const u16* __restrict__ g, const float* __restrict__ lnw,
            const float* __restrict__ lnb, u16* __restrict__ outb) {
  int bt = blockIdx.x;
  int b = bt >> 10, t = bt & 1023;
  int wv = threadIdx.x >> 6, lane = threadIdx.x & 63;
  for (int h = wv; h < HH; h += 4) {
    size_t idx = (((size_t)(b * HH + h)) * TT + t) * KK + lane;
    float v = yf[idx] + yb[idx];
    float s1 = v, s2 = v * v;
#pragma unroll
    for (int off = 32; off > 0; off >>= 1) {
      s1 += __shfl_xor(s1, off);
      s2 += __shfl_xor(s2, off);
    }
    float mu = s1 * (1.f / 64.f);
    float var = s2 * (1.f / 64.f) - mu * mu;
    float xn = (v - mu) * rsqrtf(var + 6.4e-4f);
    int d = h * 64 + lane;
    float o = xn * lnw[d] + lnb[d];
    outb[(size_t)bt * DD + d] = f2bf(o * bf2f(g[(size_t)bt * DD + d]));
  }
}

extern "C" void kernel_launch(void* const* d_in, const int* in_sizes, int n_in,
                              void* d_out, int out_size, void* d_ws, size_t ws_size,
                              hipStream_t stream) {
  const float* x      = (const float*)d_in[0];
  const float* maa_x  = (const float*)d_in[1];
  const float* maa_w  = (const float*)d_in[2];
  const float* maa_k  = (const float*)d_in[3];
  const float* maa_v  = (const float*)d_in[4];
  const float* maa_r  = (const float*)d_in[5];
  const float* maa_g  = (const float*)d_in[6];
  const float* maa_a  = (const float*)d_in[7];
  const float* w1mix  = (const float*)d_in[8];
  const float* w2mix  = (const float*)d_in[9];
  const float* tdecay = (const float*)d_in[10];
  const float* wdec1  = (const float*)d_in[11];
  const float* wdec2  = (const float*)d_in[12];
  const float* a0     = (const float*)d_in[13];
  const float* a1     = (const float*)d_in[14];
  const float* a2     = (const float*)d_in[15];
  const float* k_k    = (const float*)d_in[16];
  const float* k_a    = (const float*)d_in[17];
  const float* W_r    = (const float*)d_in[18];
  const float* W_k    = (const float*)d_in[19];
  const float* W_v    = (const float*)d_in[20];
  const float* W_g    = (const float*)d_in[21];
  const float* W_o    = (const float*)d_in[22];
  const float* lnw    = (const float*)d_in[23];
  const float* lnb    = (const float*)d_in[24];
  float* out = (float*)d_out;

  const size_t NEf = NE;
  float* F = (float*)d_ws;
  u16*   xxx_b  = (u16*)F;         // 2048x1024 bf16
  u16*   xw_b   = (u16*)(F + 1 * NEf);  // bf16; slot later reused: rfb/rbb
  u16*   xa_b   = (u16*)(F + 2 * NEf);  // bf16; slot later reused: kfb/kbw
  float* csbsb  = F + 4 * NEf;
  float* P3     = F + 3 * NEf;     // consumed by reduce8b
  float* PpartW = F + 3 * NEf;
  float* PpartA = F + 4 * NEf;     // dead before gemm_k2b writes csbsb
  float* yf     = F + 3 * NEf;     // PpartW dead after reduce8_pairb; k7 partial fwd
  float* yb     = F + 5 * NEf;     // (iclr slot freed by fusion); k7 partial bwd
  u16*   gb     = (u16*)(F + 6 * NEf);            // gate bf16
  u16*   hmixb  = (u16*)(F + 7 * NEf);            // 2048x192 bf16
  u16*   hdec_b = (u16*)(F + 7 * NEf + 524288);   // 2048x64 bf16
  u16*   ha_b   = (u16*)(F + 7 * NEf + 786432);   // 2048x64 bf16
  float* partb  = F + 7 * NEf + 917504;           // 32768 floats
  u16*   W1t    = (u16*)(F + 7 * NEf + 1048576);  // 192x1024 bf16
  u16*   wdec2t = (u16*)(F + 7 * NEf + 1146880);  // 1024x64 bf16
  u16*   a2t    = (u16*)(F + 7 * NEf + 1179648);  // 1024x64 bf16
  u16*   wdec1t = (u16*)(F + 7 * NEf + 1212416);  // 64x1024 bf16
  u16*   a1t    = (u16*)(F + 7 * NEf + 1245184);  // 64x1024 bf16
  u16*   W2t    = (u16*)(F + 7 * NEf + 1966080);  // 6x1024x32 bf16 (ends < 8*NE)
  u16* rfb = (u16*)xw_b;
  u16* rbb = rfb + NEf;
  u16* kfb = (u16*)xa_b;
  u16* kbw = kfb + NEf;
  u16* U = (u16*)(F + 8 * NEf);
  u16* xr_b = U + 0 * NEf;
  u16* xk_b = U + 1 * NEf;
  u16* xv_b = U + 2 * NEf;
  u16* xg_b = U + 3 * NEf;
  u16* rbuf = U + 4 * NEf;
  u16* kbuf = U + 5 * NEf;
  u16* vT   = U + 6 * NEf;
  u16* kkb  = U + 7 * NEf;
  u16* kkib = U + 8 * NEf;
  u16* vfT  = U + 9 * NEf;
  u16* vbT  = U + 10 * NEf;
  u16* gnb  = U + 11 * NEf;
  u16* WtR  = U + 12 * NEf;
  u16* WtK  = U + 12 * NEf + 1048576;
  u16* WtV  = U + 12 * NEf + 2097152;
  u16* WtG  = U + 12 * NEf + 3145728;
  u16* WtO  = U + 12 * NEf + 4194304;

  dim3 blk(256);

  pre<<<2256, blk, 0, stream>>>(w2mix, W2t, w1mix, W1t, wdec2, a2, wdec2t, a2t,
                                wdec1, a1, wdec1t, a1t, x, maa_x, xxx_b);

  hmix_g<<<1664, blk, 0, stream>>>(W_r, W_k, W_v, W_g, W_o,
                                   WtR, WtK, WtV, WtG, WtO,
                                   xxx_b, W1t, P3);
  reduce8b<<<1536, blk, 0, stream>>>(P3, hmixb, 393216);

  mixg<<<dim3(8, 16, 6), blk, 0, stream>>>(hmixb, W2t, x,
                                           maa_w, maa_k, maa_v, maa_r, maa_g, maa_a,
                                           xw_b, xa_b, xk_b, xv_b, xr_b, xg_b);

  gemm_bf4<<<1280, blk, 0, stream>>>(xr_b, xk_b, xv_b, xg_b,
                                     WtR, WtK, WtV, WtG,
                                     rbuf, kbuf, vT, gb,
                                     xw_b, wdec1t, PpartW, xa_b, a1t, PpartA);

  reduce8_pairb<<<dim3(512, 2), blk, 0, stream>>>(PpartW, PpartA, hdec_b, ha_b);

  // LoRA-up fused with k5a (z=0: csbs+part) and k4 (z=1: kk-normalize, iclr in-reg)
  gemm_k2b<<<dim3(16, 16, 2), blk, 0, stream>>>(hdec_b, wdec2t, tdecay, csbsb, partb,
                                                ha_b, a2t, a0,
                                                kbuf, kkb, kkib, k_k, k_a);

  // k6: 512 fwd + 512 bwd + 128 k5c = 1152 blocks
  k6_pass1<<<1152, blk, 0, stream>>>(kkb, kkib, vT, vfT, vbT,
                                     csbsb, partb, rbuf, kbuf,
                                     rfb, rbb, kfb, kbw);
  // k7: 512 fwd + 512 bwd = 1024 blocks -> yf/yb partials
  k7_pass2<<<1024, blk, 0, stream>>>(rfb, rbb, kfb, kbw, vfT, vbT, yf, yb);
  k8_gn2<<<NBT, blk, 0, stream>>>(yf, yb, gb, lnw, lnb, gnb);
  gemm_bfo<<<256, blk, 0, stream>>>(gnb, WtO, out);
}

// Round 22
// 167.628 us; speedup vs baseline: 1.0655x; 1.0151x over previous
//
#include <hip/hip_runtime.h>
#include <math.h>

#define BB 2
#define TT 1024
#define DD 1024
#define HH 16
#define KK 64
#define NBT 2048              // B*T
#define NE  2097152ULL        // B*T*D

typedef unsigned short u16;
typedef __attribute__((ext_vector_type(8))) short short8;   // 8 bf16 (4 VGPR)
typedef __attribute__((ext_vector_type(4))) short short4v;  // 4 bf16 (8B)
typedef __attribute__((ext_vector_type(4))) float f32x4;

__device__ __forceinline__ float bf2f(u16 u) {
  union { unsigned int i; float f; } v; v.i = ((unsigned int)u) << 16; return v.f;
}
__device__ __forceinline__ u16 f2bf(float x) {
  union { float f; unsigned int u; } v; v.f = x;
  unsigned int r = v.u + 0x7fffu + ((v.u >> 16) & 1u);
  return (u16)(r >> 16);
}
__device__ __forceinline__ f32x4 MFMA(short8 a, short8 b, f32x4 c) {
  return __builtin_amdgcn_mfma_f32_16x16x32_bf16(a, b, c, 0, 0, 0);
}
// XOR swizzle for [64 rows][128B] LDS tiles (G4: 128B rows are 32-way conflict)
__device__ __forceinline__ int swzb(int row, int kbyte) {
  return row * 128 + (kbyte ^ ((row & 7) << 4));
}
__device__ __forceinline__ void gload16(const void* g, void* l) {
  __builtin_amdgcn_global_load_lds((const __attribute__((address_space(1))) void*)g,
                                   (__attribute__((address_space(3))) void*)l, 16, 0, 0);
}

// ---------------- pre: small transposes + k1_xxx + dxprev (flat grid 2256) ----------------
__global__ __launch_bounds__(256)
void pre(const float* __restrict__ W2, u16* __restrict__ W2t,
         const float* __restrict__ W1, u16* __restrict__ W1t,
         const float* __restrict__ wdec2, const float* __restrict__ a2,
         u16* __restrict__ wdec2t, u16* __restrict__ a2t,
         const float* __restrict__ wdec1, const float* __restrict__ a1,
         u16* __restrict__ wdec1t, u16* __restrict__ a1t,
         const float* __restrict__ x, const float* __restrict__ maa_x,
         u16* __restrict__ xxx_b, u16* __restrict__ dxb) {
  __shared__ float tl[64][65];
  int idx = blockIdx.x;
  int tid = threadIdx.x;
  if (idx < 96) {
    int s = idx >> 4, d0 = (idx & 15) * 64;
    int c = tid & 63, r0 = (tid >> 6) * 8;
#pragma unroll
    for (int j = 0; j < 8; ++j)
      tl[r0 + j][c] = W2[(size_t)(s * 32 + r0 + j) * 1024 + d0 + c];
    __syncthreads();
    int d = tid >> 2, ms = (tid & 3) * 8;
    u16 o[8];
#pragma unroll
    for (int j = 0; j < 8; ++j) o[j] = f2bf(tl[ms + j][d]);
    *(short8*)(W2t + ((size_t)s * 1024 + d0 + d) * 32 + ms) = *(short8*)o;
  } else if (idx < 144) {
    int i = idx - 96;
    int k0 = (i & 15) * 64, n0 = (i >> 4) * 64;
    int r = tid >> 2, c0 = (tid & 3) * 16;
#pragma unroll
    for (int j = 0; j < 16; j += 4) {
      f32x4 v = *(const f32x4*)(W1 + (size_t)(k0 + r) * 192 + n0 + c0 + j);
      tl[r][c0 + j + 0] = v[0]; tl[r][c0 + j + 1] = v[1];
      tl[r][c0 + j + 2] = v[2]; tl[r][c0 + j + 3] = v[3];
    }
    __syncthreads();
    u16 o[16];
#pragma unroll
    for (int j = 0; j < 16; ++j) o[j] = f2bf(tl[c0 + j][r]);
    *(short8*)(W1t + (size_t)(n0 + r) * 1024 + k0 + c0) = *(short8*)(o);
    *(short8*)(W1t + (size_t)(n0 + r) * 1024 + k0 + c0 + 8) = *(short8*)(o + 8);
  } else if (idx < 176) {
    int i = idx - 144;
    int zz = i >> 4;
    const float* W = zz ? a2 : wdec2;
    u16* Wt = zz ? a2t : wdec2t;
    int n0 = (i & 15) * 64;
    int r = tid >> 2, c0 = (tid & 3) * 16;
#pragma unroll
    for (int j = 0; j < 16; j += 4) {
      f32x4 v = *(const f32x4*)(W + (size_t)r * 1024 + n0 + c0 + j);
      tl[r][c0 + j + 0] = v[0]; tl[r][c0 + j + 1] = v[1];
      tl[r][c0 + j + 2] = v[2]; tl[r][c0 + j + 3] = v[3];
    }
    __syncthreads();
    u16 o[16];
#pragma unroll
    for (int j = 0; j < 16; ++j) o[j] = f2bf(tl[c0 + j][r]);
    *(short8*)(Wt + (size_t)(n0 + r) * 64 + c0) = *(short8*)(o);
    *(short8*)(Wt + (size_t)(n0 + r) * 64 + c0 + 8) = *(short8*)(o + 8);
  } else if (idx < 208) {
    int i = idx - 176;
    int zz = i >> 4;
    const float* W = zz ? a1 : wdec1;
    u16* Wt = zz ? a1t : wdec1t;
    int k0 = (i & 15) * 64;
    int r = tid >> 2, c0 = (tid & 3) * 16;
#pragma unroll
    for (int j = 0; j < 16; j += 4) {
      f32x4 v = *(const f32x4*)(W + (size_t)(k0 + r) * 64 + c0 + j);
      tl[r][c0 + j + 0] = v[0]; tl[r][c0 + j + 1] = v[1];
      tl[r][c0 + j + 2] = v[2]; tl[r][c0 + j + 3] = v[3];
    }
    __syncthreads();
    u16 o[16];
#pragma unroll
    for (int j = 0; j < 16; ++j) o[j] = f2bf(tl[c0 + j][r]);
    *(short8*)(Wt + (size_t)r * 1024 + k0 + c0) = *(short8*)(o);
    *(short8*)(Wt + (size_t)r * 1024 + k0 + c0 + 8) = *(short8*)(o + 8);
  } else {
    int row = idx - 208;
    int t = row & (TT - 1);
    int d0 = tid * 4;
    size_t g = (size_t)row * DD + d0;
    f32x4 xc = *(const f32x4*)(x + g);
    f32x4 xl = {0.f, 0.f, 0.f, 0.f}, xr = {0.f, 0.f, 0.f, 0.f};
    if (t != 0) xl = *(const f32x4*)(x + g - DD);
    if (t != TT - 1) xr = *(const f32x4*)(x + g + DD);
    f32x4 mx = *(const f32x4*)(maa_x + d0);
    u16 o[4], od[4];
#pragma unroll
    for (int j = 0; j < 4; ++j) {
      float dx = 0.5f * (xl[j] + xr[j]) - xc[j];
      o[j] = f2bf(xc[j] + dx * mx[j]);
      od[j] = f2bf(dx);
    }
    *(short4v*)(xxx_b + g) = *(short4v*)o;
    *(short4v*)(dxb + g) = *(short4v*)od;
  }
}

// ---------------- hmix_g fused with big-5 W transposes (flat grid 1664) ----------------
__global__ __launch_bounds__(256)
void hmix_g(const float* __restrict__ W_r, const float* __restrict__ W_k,
            const float* __restrict__ W_v, const float* __restrict__ W_g,
            const float* __restrict__ W_o,
            u16* __restrict__ TR, u16* __restrict__ TK, u16* __restrict__ TV,
            u16* __restrict__ TG, u16* __restrict__ TO,
            const u16* __restrict__ xxx_b, const u16* __restrict__ W1t,
            float* __restrict__ P3) {
  __shared__ float tl[64][65];
  __shared__ u16 As[4096];  // 128x32
  __shared__ u16 Bs[2048];  // 64x32
  int idx = blockIdx.x;
  int tid = threadIdx.x;
  if (idx < 1280) {
    int z = idx >> 8, rem = idx & 255;
    const float* W = (z == 0) ? W_r : (z == 1) ? W_k : (z == 2) ? W_v : (z == 3) ? W_g : W_o;
    u16* Wt = (z == 0) ? TR : (z == 1) ? TK : (z == 2) ? TV : (z == 3) ? TG : TO;
    int k0 = (rem & 15) * 64, n0 = (rem >> 4) * 64;
    int r = tid >> 2, c0 = (tid & 3) * 16;
#pragma unroll
    for (int j = 0; j < 16; j += 4) {
      f32x4 v = *(const f32x4*)(W + (size_t)(k0 + r) * 1024 + n0 + c0 + j);
      tl[r][c0 + j + 0] = v[0]; tl[r][c0 + j + 1] = v[1];
      tl[r][c0 + j + 2] = v[2]; tl[r][c0 + j + 3] = v[3];
    }
    __syncthreads();
    u16 o[16];
#pragma unroll
    for (int j = 0; j < 16; ++j) o[j] = f2bf(tl[c0 + j][r]);
    *(short8*)(Wt + (size_t)(n0 + r) * 1024 + k0 + c0) = *(short8*)(o);
    *(short8*)(Wt + (size_t)(n0 + r) * 1024 + k0 + c0 + 8) = *(short8*)(o + 8);
    return;
  }
  int i = idx - 1280;                 // 0..383
  int n0 = (i % 3) * 64;
  int q = i / 3;                      // 0..127
  int m0 = (q & 15) * 128;
  int kb = q >> 4;                    // 0..7
  int w = tid >> 6, lane = tid & 63;
  int mq = w >> 1, nq = w & 1;
  f32x4 acc[4][2];
#pragma unroll
  for (int ii = 0; ii < 4; ++ii)
#pragma unroll
    for (int j = 0; j < 2; ++j) acc[ii][j] = {0.f, 0.f, 0.f, 0.f};
  for (int t = 0; t < 4; ++t) {
    int k0 = kb * 128 + t * 32;
#pragma unroll
    for (int c2 = 0; c2 < 2; ++c2) {
      int ch = w * 2 + c2;
      int row = ch * 16 + (lane >> 2);
      gload16(xxx_b + (size_t)(m0 + row) * 1024 + k0 + (lane & 3) * 8, As + ch * 512);
    }
    {
      int row = w * 16 + (lane >> 2);
      gload16(W1t + (size_t)(n0 + row) * 1024 + k0 + (lane & 3) * 8, Bs + w * 512);
    }
    __syncthreads();
    short8 a[4], b[2];
#pragma unroll
    for (int mf = 0; mf < 4; ++mf)
      a[mf] = *(const short8*)(As + (mq * 64 + mf * 16 + (lane & 15)) * 32 + (lane >> 4) * 8);
#pragma unroll
    for (int nf = 0; nf < 2; ++nf)
      b[nf] = *(const short8*)(Bs + (nq * 32 + nf * 16 + (lane & 15)) * 32 + (lane >> 4) * 8);
#pragma unroll
    for (int mf = 0; mf < 4; ++mf)
#pragma unroll
      for (int nf = 0; nf < 2; ++nf) acc[mf][nf] = MFMA(a[mf], b[nf], acc[mf][nf]);
    __syncthreads();
  }
#pragma unroll
  for (int mf = 0; mf < 4; ++mf) {
#pragma unroll
    for (int nf = 0; nf < 2; ++nf) {
      int mb = m0 + mq * 64 + mf * 16 + (lane >> 4) * 4;
      int n = n0 + nq * 32 + nf * 16 + (lane & 15);
#pragma unroll
      for (int r = 0; r < 4; ++r)
        P3[(size_t)kb * 393216 + (size_t)(mb + r) * 192 + n] = acc[mf][nf][r];
    }
  }
}

// ---------------- reduce 8 partials -> tanh -> bf16 (hmix) ----------------
__global__ __launch_bounds__(256)
void reduce8b(const float* __restrict__ P, u16* __restrict__ C, int total) {
  size_t i = (size_t)blockIdx.x * 256 + threadIdx.x;
  float s = 0.f;
#pragma unroll
  for (int kb = 0; kb < 8; ++kb) s += P[(size_t)kb * total + i];
  C[i] = f2bf(tanhf(s));
}

// ---------------- fused pair reduce -> bf16 ----------------
__global__ __launch_bounds__(256)
void reduce8_pairb(const float* __restrict__ Pw, const float* __restrict__ Pa,
                   u16* __restrict__ hdec_b, u16* __restrict__ ha_b) {
  int z = blockIdx.y;
  size_t i = (size_t)blockIdx.x * 256 + threadIdx.x;
  const float* P = z ? Pa : Pw;
  float s = 0.f;
#pragma unroll
  for (int kb = 0; kb < 8; ++kb) s += P[(size_t)kb * 131072 + i];
  if (z) ha_b[i] = f2bf(s);
  else hdec_b[i] = f2bf(tanhf(s));
}

// ---------------- mixg v4: MFMA mix + LDS round-trip + dxprev-based epilogue ----------------
__global__ __launch_bounds__(256)
void mixg(const u16* __restrict__ hmixb, const u16* __restrict__ W2t,
          const float* __restrict__ x, const u16* __restrict__ dxb,
          const float* __restrict__ maa_w, const float* __restrict__ maa_k,
          const float* __restrict__ maa_v, const float* __restrict__ maa_r,
          const float* __restrict__ maa_g, const float* __restrict__ maa_a,
          u16* __restrict__ xw_b, u16* __restrict__ xa_b,
          u16* __restrict__ xk_b, u16* __restrict__ xv_b,
          u16* __restrict__ xr_b, u16* __restrict__ xg_b) {
  __shared__ u16 shm[16384];
  u16* As = shm;
  u16* Bs = shm + 4096;
  u16* mixt = shm;
  int s = blockIdx.z;
  int m0 = blockIdx.y * 128, n0 = blockIdx.x * 128;
  int tid = threadIdx.x, w = tid >> 6, lane = tid & 63;
  int mq = w >> 1, nq = w & 1;
#pragma unroll
  for (int c2 = 0; c2 < 2; ++c2) {
    int ch = w * 2 + c2;
    int row = ch * 16 + (lane >> 2);
    gload16(hmixb + (size_t)(m0 + row) * 192 + s * 32 + (lane & 3) * 8, As + ch * 512);
    gload16(W2t + ((size_t)s * 1024 + n0 + row) * 32 + (lane & 3) * 8, Bs + ch * 512);
  }
  __syncthreads();
  short8 a[4], b[4];
#pragma unroll
  for (int mf = 0; mf < 4; ++mf)
    a[mf] = *(const short8*)(As + (mq * 64 + mf * 16 + (lane & 15)) * 32 + (lane >> 4) * 8);
#pragma unroll
  for (int nf = 0; nf < 4; ++nf)
    b[nf] = *(const short8*)(Bs + (nq * 64 + nf * 16 + (lane & 15)) * 32 + (lane >> 4) * 8);
  f32x4 acc[4][4];
#pragma unroll
  for (int mf = 0; mf < 4; ++mf)
#pragma unroll
    for (int nf = 0; nf < 4; ++nf) {
      f32x4 z = {0.f, 0.f, 0.f, 0.f};
      acc[mf][nf] = MFMA(a[mf], b[nf], z);
    }
  __syncthreads();
#pragma unroll
  for (int mf = 0; mf < 4; ++mf) {
#pragma unroll
    for (int nf = 0; nf < 4; ++nf) {
      int col = nq * 64 + nf * 16 + (lane & 15);
#pragma unroll
      for (int r = 0; r < 4; ++r) {
        int row = mq * 64 + mf * 16 + (lane >> 4) * 4 + r;
        mixt[row * 128 + col] = f2bf(acc[mf][nf][r]);
      }
    }
  }
  __syncthreads();
  const float* maa = (s == 0) ? maa_w : (s == 1) ? maa_k : (s == 2) ? maa_v
                    : (s == 3) ? maa_r : (s == 4) ? maa_g : maa_a;
  u16* dst = (s == 0) ? xw_b : (s == 1) ? xk_b : (s == 2) ? xv_b
            : (s == 3) ? xr_b : (s == 4) ? xg_b : xa_b;
  int cg = tid & 15;
  int rowg = tid >> 4;
  int d0 = n0 + cg * 8;
  f32x4 ma0 = *(const f32x4*)(maa + d0);
  f32x4 ma1 = *(const f32x4*)(maa + d0 + 4);
#pragma unroll
  for (int rr = 0; rr < 8; ++rr) {
    int row = rr * 16 + rowg;
    int m = m0 + row;
    size_t g = (size_t)m * DD + d0;
    f32x4 xc0 = *(const f32x4*)(x + g);
    f32x4 xc1 = *(const f32x4*)(x + g + 4);
    short8 dv = *(const short8*)(dxb + g);
    short8 mv = *(const short8*)(mixt + row * 128 + cg * 8);
    u16 o[8];
#pragma unroll
    for (int j = 0; j < 8; ++j) {
      float xcj = (j < 4) ? xc0[j & 3] : xc1[j & 3];
      float maj = (j < 4) ? ma0[j & 3] : ma1[j & 3];
      float dx = bf2f((u16)dv[j]);
      o[j] = f2bf(xcj + dx * (maj + bf2f((u16)mv[j])));
    }
    *(short8*)(dst + g) = *(short8*)o;
  }
}

// ---------------- fused 4-way bf16 MFMA projection GEMM + skinny LoRA-down ----------------
__global__ __launch_bounds__(256)
void gemm_bf4(const u16* __restrict__ xr, const u16* __restrict__ xk,
              const u16* __restrict__ xv, const u16* __restrict__ xg,
              const u16* __restrict__ WtR, const u16* __restrict__ WtK,
              const u16* __restrict__ WtV, const u16* __restrict__ WtG,
              u16* __restrict__ rbuf, u16* __restrict__ kbuf,
              u16* __restrict__ vT, u16* __restrict__ gb,
              const u16* __restrict__ xw_b, const u16* __restrict__ wdec1t,
              float* __restrict__ PpartW,
              const u16* __restrict__ xa_b, const u16* __restrict__ a1t,
              float* __restrict__ PpartA) {
  __shared__ u16 As[2][4096];
  __shared__ u16 Bs[2][2048];
  int wgid = blockIdx.x;
  int tid = threadIdx.x, w = tid >> 6, lane = tid & 63;
  int mq = w >> 1, nq = w & 1;
  if (wgid >= 1024) {
    int i = wgid - 1024;
    int m0 = (i & 15) * 128;
    int kb = (i >> 4) & 7;
    int z = i >> 7;
    const u16* A = z ? xa_b : xw_b;
    const u16* Bt = z ? a1t : wdec1t;
    float* P = z ? PpartA : PpartW;
    f32x4 acc[4][2];
#pragma unroll
    for (int ii = 0; ii < 4; ++ii)
#pragma unroll
      for (int j = 0; j < 2; ++j) acc[ii][j] = {0.f, 0.f, 0.f, 0.f};
    for (int t = 0; t < 4; ++t) {
      int k0 = kb * 128 + t * 32;
#pragma unroll
      for (int c2 = 0; c2 < 2; ++c2) {
        int ch = w * 2 + c2;
        int row = ch * 16 + (lane >> 2);
        gload16(A + (size_t)(m0 + row) * 1024 + k0 + (lane & 3) * 8, As[0] + ch * 512);
      }
      {
        int row = w * 16 + (lane >> 2);
        gload16(Bt + (size_t)row * 1024 + k0 + (lane & 3) * 8, Bs[0] + w * 512);
      }
      __syncthreads();
      short8 a[4], b[2];
#pragma unroll
      for (int mf = 0; mf < 4; ++mf)
        a[mf] = *(const short8*)(As[0] + (mq * 64 + mf * 16 + (lane & 15)) * 32 + (lane >> 4) * 8);
#pragma unroll
      for (int nf = 0; nf < 2; ++nf)
        b[nf] = *(const short8*)(Bs[0] + (nq * 32 + nf * 16 + (lane & 15)) * 32 + (lane >> 4) * 8);
#pragma unroll
      for (int mf = 0; mf < 4; ++mf)
#pragma unroll
        for (int nf = 0; nf < 2; ++nf) acc[mf][nf] = MFMA(a[mf], b[nf], acc[mf][nf]);
      __syncthreads();
    }
#pragma unroll
    for (int mf = 0; mf < 4; ++mf) {
#pragma unroll
      for (int nf = 0; nf < 2; ++nf) {
        int mb = m0 + mq * 64 + mf * 16 + (lane >> 4) * 4;
        int n = nq * 32 + nf * 16 + (lane & 15);
#pragma unroll
        for (int r = 0; r < 4; ++r)
          P[(size_t)kb * 131072 + (size_t)(mb + r) * 64 + n] = acc[mf][nf][r];
      }
    }
    return;
  }
  int xcd = wgid & 7, idx = wgid >> 3;
  int z = xcd >> 1, mhalf = xcd & 1;
  int mloc = idx & 7, nt = idx >> 3;
  int m0 = (mhalf * 8 + mloc) * 128;
  int n0 = nt * 64;
  const u16* A = (z == 0) ? xr : (z == 1) ? xk : (z == 2) ? xv : xg;
  const u16* Bt = (z == 0) ? WtR : (z == 1) ? WtK : (z == 2) ? WtV : WtG;
  int arow0 = (w * 2) * 16 + (lane >> 2);
  int arow1 = (w * 2 + 1) * 16 + (lane >> 2);
  int brow = w * 16 + (lane >> 2);
  int kc = (lane & 3) * 8;
  f32x4 acc[4][2];
#pragma unroll
  for (int i = 0; i < 4; ++i)
#pragma unroll
    for (int j = 0; j < 2; ++j) acc[i][j] = {0.f, 0.f, 0.f, 0.f};
  gload16(A + (size_t)(m0 + arow0) * 1024 + kc, As[0] + (w * 2) * 512);
  gload16(A + (size_t)(m0 + arow1) * 1024 + kc, As[0] + (w * 2 + 1) * 512);
  gload16(Bt + (size_t)(n0 + brow) * 1024 + kc, Bs[0] + w * 512);
  __syncthreads();
  for (int t = 0; t < 32; ++t) {
    int cur = t & 1;
    if (t < 31) {
      int kn = (t + 1) * 32;
      gload16(A + (size_t)(m0 + arow0) * 1024 + kn + kc, As[cur ^ 1] + (w * 2) * 512);
      gload16(A + (size_t)(m0 + arow1) * 1024 + kn + kc, As[cur ^ 1] + (w * 2 + 1) * 512);
      gload16(Bt + (size_t)(n0 + brow) * 1024 + kn + kc, Bs[cur ^ 1] + w * 512);
    }
    short8 a[4], b[2];
#pragma unroll
    for (int mf = 0; mf < 4; ++mf)
      a[mf] = *(const short8*)(As[cur] + (mq * 64 + mf * 16 + (lane & 15)) * 32 + (lane >> 4) * 8);
#pragma unroll
    for (int nf = 0; nf < 2; ++nf)
      b[nf] = *(const short8*)(Bs[cur] + (nq * 32 + nf * 16 + (lane & 15)) * 32 + (lane >> 4) * 8);
#pragma unroll
    for (int mf = 0; mf < 4; ++mf)
#pragma unroll
      for (int nf = 0; nf < 2; ++nf) acc[mf][nf] = MFMA(a[mf], b[nf], acc[mf][nf]);
    __syncthreads();
  }
#pragma unroll
  for (int mf = 0; mf < 4; ++mf) {
#pragma unroll
    for (int nf = 0; nf < 2; ++nf) {
      int mb = m0 + mq * 64 + mf * 16 + (lane >> 4) * 4;
      int n = n0 + nq * 32 + nf * 16 + (lane & 15);
      if (z == 2) {  // VTB: vT[b*H+h][k][t] bf16
        u16 o[4];
#pragma unroll
        for (int r = 0; r < 4; ++r) o[r] = f2bf(acc[mf][nf][r]);
        int b2 = mb >> 10, t = mb & 1023;
        *(short4v*)(vT + (((size_t)(b2 * HH + (n >> 6))) * KK + (n & 63)) * TT + t) = *(short4v*)o;
      } else if (z == 3) {  // gate: silu -> bf16 flat
#pragma unroll
        for (int r = 0; r < 4; ++r) {
          int m = mb + r;
          float v = acc[mf][nf][r];
          gb[(size_t)m * 1024 + n] = f2bf(v / (1.f + __expf(-v)));
        }
      } else {  // HEADB bf16 head layout
        u16* C = (z == 0) ? rbuf : kbuf;
#pragma unroll
        for (int r = 0; r < 4; ++r) {
          int m = mb + r;
          int b2 = m >> 10, t = m & 1023;
          C[(((size_t)(b2 * HH + (n >> 6))) * TT + t) * KK + (n & 63)] = f2bf(acc[mf][nf][r]);
        }
      }
    }
  }
}

// ---------------- W_o bf16 MFMA GEMM (128x64, BK=32 dbuf, XCD-partitioned 256 blocks) ----------------
__global__ __launch_bounds__(256)
void gemm_bfo(const u16* __restrict__ A, const u16* __restrict__ Bt,
              float* __restrict__ C) {
  __shared__ u16 As[2][4096];
  __shared__ u16 Bs[2][2048];
  int wgid = blockIdx.x;
  int xcd = wgid & 7, idx = wgid >> 3;
  int mloc = idx & 1, nt = idx >> 1;
  int m0 = (xcd * 2 + mloc) * 128;
  int n0 = nt * 64;
  int tid = threadIdx.x, w = tid >> 6, lane = tid & 63;
  int mq = w >> 1, nq = w & 1;
  int arow0 = (w * 2) * 16 + (lane >> 2);
  int arow1 = (w * 2 + 1) * 16 + (lane >> 2);
  int brow = w * 16 + (lane >> 2);
  int kc = (lane & 3) * 8;
  f32x4 acc[4][2];
#pragma unroll
  for (int i = 0; i < 4; ++i)
#pragma unroll
    for (int j = 0; j < 2; ++j) acc[i][j] = {0.f, 0.f, 0.f, 0.f};
  gload16(A + (size_t)(m0 + arow0) * 1024 + kc, As[0] + (w * 2) * 512);
  gload16(A + (size_t)(m0 + arow1) * 1024 + kc, As[0] + (w * 2 + 1) * 512);
  gload16(Bt + (size_t)(n0 + brow) * 1024 + kc, Bs[0] + w * 512);
  __syncthreads();
  for (int t = 0; t < 32; ++t) {
    int cur = t & 1;
    if (t < 31) {
      int kn = (t + 1) * 32;
      gload16(A + (size_t)(m0 + arow0) * 1024 + kn + kc, As[cur ^ 1] + (w * 2) * 512);
      gload16(A + (size_t)(m0 + arow1) * 1024 + kn + kc, As[cur ^ 1] + (w * 2 + 1) * 512);
      gload16(Bt + (size_t)(n0 + brow) * 1024 + kn + kc, Bs[cur ^ 1] + w * 512);
    }
    short8 a[4], b[2];
#pragma unroll
    for (int mf = 0; mf < 4; ++mf)
      a[mf] = *(const short8*)(As[cur] + (mq * 64 + mf * 16 + (lane & 15)) * 32 + (lane >> 4) * 8);
#pragma unroll
    for (int nf = 0; nf < 2; ++nf)
      b[nf] = *(const short8*)(Bs[cur] + (nq * 32 + nf * 16 + (lane & 15)) * 32 + (lane >> 4) * 8);
#pragma unroll
    for (int mf = 0; mf < 4; ++mf)
#pragma unroll
      for (int nf = 0; nf < 2; ++nf) acc[mf][nf] = MFMA(a[mf], b[nf], acc[mf][nf]);
    __syncthreads();
  }
#pragma unroll
  for (int mf = 0; mf < 4; ++mf) {
#pragma unroll
    for (int nf = 0; nf < 2; ++nf) {
      int mb = m0 + mq * 64 + mf * 16 + (lane >> 4) * 4;
      int n = n0 + nq * 32 + nf * 16 + (lane & 15);
#pragma unroll
      for (int r = 0; r < 4; ++r)
        C[(size_t)(mb + r) * 1024 + n] = acc[mf][nf][r];
    }
  }
}

// ---------------- gemm_k2b: dual K=64 bf16 MFMA LoRA-up, fused k5a (z=0) + k4 (z=1) ----------------
__global__ __launch_bounds__(256)
void gemm_k2b(const u16* __restrict__ A0, const u16* __restrict__ B0t,
              const float* __restrict__ bias0,
              float* __restrict__ csbs, float* __restrict__ part,
              const u16* __restrict__ A1, const u16* __restrict__ B1t,
              const float* __restrict__ bias1,
              u16* __restrict__ kbuf, u16* __restrict__ kkb, u16* __restrict__ kkib,
              const float* __restrict__ k_k, const float* __restrict__ k_a) {
  __shared__ u16 As[8192];  // [2 ks][128 rows][32 k]
  __shared__ u16 Bs[4096];  // [2 ks][64 rows][32 k]
  __shared__ float hsum[128][2];
  int z = blockIdx.z;
  const u16* A = z ? A1 : A0;
  const u16* Bt = z ? B1t : B0t;
  const float* bias = z ? bias1 : bias0;
  int n0 = blockIdx.x * 64, m0 = blockIdx.y * 128;
  int tid = threadIdx.x, w = tid >> 6, lane = tid & 63;
  int mq = w >> 1, nq = w & 1;
#pragma unroll
  for (int j = 0; j < 4; ++j) {
    int q = w * 4 + j;
    int ks = q >> 3, rg = q & 7;
    int row = rg * 16 + (lane >> 2);
    int kc = ks * 32 + (lane & 3) * 8;
    gload16(A + (size_t)(m0 + row) * 64 + kc, As + q * 512);
  }
#pragma unroll
  for (int j = 0; j < 2; ++j) {
    int q = w * 2 + j;
    int ks = q >> 2, rg = q & 3;
    int row = rg * 16 + (lane >> 2);
    int kc = ks * 32 + (lane & 3) * 8;
    gload16(Bt + (size_t)(n0 + row) * 64 + kc, Bs + q * 512);
  }
  __syncthreads();
  f32x4 acc[4][2];
#pragma unroll
  for (int i = 0; i < 4; ++i)
#pragma unroll
    for (int j = 0; j < 2; ++j) acc[i][j] = {0.f, 0.f, 0.f, 0.f};
#pragma unroll
  for (int ks = 0; ks < 2; ++ks) {
    short8 a[4], b[2];
#pragma unroll
    for (int mf = 0; mf < 4; ++mf)
      a[mf] = *(const short8*)(As + ks * 4096 + (mq * 64 + mf * 16 + (lane & 15)) * 32 + (lane >> 4) * 8);
#pragma unroll
    for (int nf = 0; nf < 2; ++nf)
      b[nf] = *(const short8*)(Bs + ks * 2048 + (nq * 32 + nf * 16 + (lane & 15)) * 32 + (lane >> 4) * 8);
#pragma unroll
    for (int mf = 0; mf < 4; ++mf)
#pragma unroll
      for (int nf = 0; nf < 2; ++nf) acc[mf][nf] = MFMA(a[mf], b[nf], acc[mf][nf]);
  }
  int b2 = m0 >> 10, h = n0 >> 6;
  int bh = b2 * HH + h;
  int jj = lane & 15, g = lane >> 4;
  if (z == 0) {
    float psum[2] = {0.f, 0.f};
#pragma unroll
    for (int mf = 0; mf < 4; ++mf) {
      int mb = m0 + mq * 64 + mf * 16 + g * 4;
#pragma unroll
      for (int nf = 0; nf < 2; ++nf) {
        int n = n0 + nq * 32 + nf * 16 + jj;
        float bv = bias[n];
#pragma unroll
        for (int r = 0; r < 4; ++r) {
          int t = (mb + r) & 1023;
          float wh = -expf(acc[mf][nf][r] + bv);
          csbs[(((size_t)bh) * TT + t) * KK + (n & 63)] = wh;
          psum[nf] += wh;
        }
      }
    }
#pragma unroll
    for (int nf = 0; nf < 2; ++nf) {
      psum[nf] += __shfl_xor(psum[nf], 16);
      psum[nf] += __shfl_xor(psum[nf], 32);
    }
    if (lane < 16) {
      int c = ((m0 & 1023) >> 6) + mq;
#pragma unroll
      for (int nf = 0; nf < 2; ++nf)
        part[((size_t)bh * 16 + c) * 64 + nq * 32 + nf * 16 + jj] = psum[nf];
    }
  } else {
    float kk2[2], ka2[2], icv[4][2][4], kvf[4][2][4];
#pragma unroll
    for (int nf = 0; nf < 2; ++nf) {
      int n = n0 + nq * 32 + nf * 16 + jj;
      kk2[nf] = k_k[n];
      ka2[nf] = k_a[n];
    }
#pragma unroll
    for (int mf = 0; mf < 4; ++mf) {
      int mb = m0 + mq * 64 + mf * 16 + g * 4;
#pragma unroll
      for (int nf = 0; nf < 2; ++nf) {
        int n = n0 + nq * 32 + nf * 16 + jj;
        float bv = bias[n];
#pragma unroll
        for (int r = 0; r < 4; ++r) {
          int t = (mb + r) & 1023;
          size_t gidx = (((size_t)bh) * TT + t) * KK + (n & 63);
          icv[mf][nf][r] = 1.f / (1.f + expf(-(acc[mf][nf][r] + bv)));
          kvf[mf][nf][r] = bf2f(kbuf[gidx]);
        }
      }
    }
#pragma unroll
    for (int mf = 0; mf < 4; ++mf) {
#pragma unroll
      for (int r = 0; r < 4; ++r) {
        float s = 0.f;
#pragma unroll
        for (int nf = 0; nf < 2; ++nf) {
          float kkh = kvf[mf][nf][r] * kk2[nf];
          s += kkh * kkh;
        }
        s += __shfl_xor(s, 1);
        s += __shfl_xor(s, 2);
        s += __shfl_xor(s, 4);
        s += __shfl_xor(s, 8);
        if (jj == 0) hsum[mq * 64 + mf * 16 + g * 4 + r][nq] = s;
      }
    }
    __syncthreads();
#pragma unroll
    for (int mf = 0; mf < 4; ++mf) {
      int mb = m0 + mq * 64 + mf * 16 + g * 4;
#pragma unroll
      for (int r = 0; r < 4; ++r) {
        int rl = mq * 64 + mf * 16 + g * 4 + r;
        float ss = hsum[rl][0] + hsum[rl][1];
        float nrm = fmaxf(sqrtf(ss), 1e-12f);
        int t = (mb + r) & 1023;
#pragma unroll
        for (int nf = 0; nf < 2; ++nf) {
          int n = n0 + nq * 32 + nf * 16 + jj;
          size_t gidx = (((size_t)bh) * TT + t) * KK + (n & 63);
          float kkh = kvf[mf][nf][r] * kk2[nf];
          float kkv = kkh / nrm;
          float ic = icv[mf][nf][r];
          kkb[gidx] = f2bf(kkv);
          kkib[gidx] = f2bf(kkv * ic);
          kbuf[gidx] = f2bf(kvf[mf][nf][r] * (1.f + (ic - 1.f) * ka2[nf]));
        }
      }
    }
  }
}

// ---------------- attention tile helpers (bf16 MFMA, T5 setprio on MFMA clusters) ----------------
struct SReg { short8 a0, a1, b0, b1; };
template <int RSA, int RSB>
__device__ __forceinline__ void sload(const u16* ka, const u16* vb, SReg& r) {
  int t0 = threadIdx.x, t1 = threadIdx.x + 256;
  r.a0 = *(const short8*)(ka + (size_t)(t0 >> 3) * RSA + (t0 & 7) * 8);
  r.a1 = *(const short8*)(ka + (size_t)(t1 >> 3) * RSA + (t1 & 7) * 8);
  r.b0 = *(const short8*)(vb + (size_t)(t0 >> 3) * RSB + (t0 & 7) * 8);
  r.b1 = *(const short8*)(vb + (size_t)(t1 >> 3) * RSB + (t1 & 7) * 8);
}
__device__ __forceinline__ void swrite(u16* Kt, u16* Vt, const SReg& r) {
  int t0 = threadIdx.x, t1 = threadIdx.x + 256;
  *(short8*)((char*)Kt + swzb(t0 >> 3, (t0 & 7) * 16)) = r.a0;
  *(short8*)((char*)Kt + swzb(t1 >> 3, (t1 & 7) * 16)) = r.a1;
  *(short8*)((char*)Vt + swzb(t0 >> 3, (t0 & 7) * 16)) = r.b0;
  *(short8*)((char*)Vt + swzb(t1 >> 3, (t1 & 7) * 16)) = r.b1;
}
template <int MASK>  // 0 none, 1 jl<il, 2 jl>il, 3 jl<=il
__device__ __forceinline__ void store_S(const f32x4 s[4], u16* St, int lane, int w) {
  int ig0 = w * 16 + (lane >> 4) * 4;
#pragma unroll
  for (int jf = 0; jf < 4; ++jf) {
    int jl = jf * 16 + (lane & 15);
#pragma unroll
    for (int r = 0; r < 4; ++r) {
      int il = ig0 + r;
      float v = s[jf][r];
      if (MASK == 1 && !(jl < il)) v = 0.f;
      if (MASK == 2 && !(jl > il)) v = 0.f;
      if (MASK == 3 && !(jl <= il)) v = 0.f;
      *(u16*)((char*)St + swzb(il, jl * 2)) = f2bf(v);
    }
  }
}
__device__ __forceinline__ void smm(short8 a0, short8 a1, const u16* Kt, f32x4 s[4], int lane) {
  __builtin_amdgcn_s_setprio(1);
#pragma unroll
  for (int jf = 0; jf < 4; ++jf) {
    f32x4 z = {0.f, 0.f, 0.f, 0.f};
    short8 kb0 = *(const short8*)((const char*)Kt + swzb(jf * 16 + (lane & 15), (lane >> 4) * 16));
    z = MFMA(a0, kb0, z);
    short8 kb1 = *(const short8*)((const char*)Kt + swzb(jf * 16 + (lane & 15), 64 + (lane >> 4) * 16));
    z = MFMA(a1, kb1, z);
    s[jf] = z;
  }
  __builtin_amdgcn_s_setprio(0);
}
__device__ __forceinline__ void pv(const u16* St, const u16* Vt, f32x4 acc[4], int lane, int w) {
  __builtin_amdgcn_s_setprio(1);
#pragma unroll
  for (int ks = 0; ks < 2; ++ks) {
    short8 a = *(const short8*)((const char*)St + swzb(w * 16 + (lane & 15), ks * 64 + (lane >> 4) * 16));
#pragma unroll
    for (int cf = 0; cf < 4; ++cf) {
      short8 b = *(const short8*)((const char*)Vt + swzb(cf * 16 + (lane & 15), ks * 64 + (lane >> 4) * 16));
      acc[cf] = MFMA(a, b, acc[cf]);
    }
  }
  __builtin_amdgcn_s_setprio(0);
}

// ---------------- K6: pass 1, fwd/bwd split (wg<512 fwd, 512..1023 bwd, >=1024 k5c) ----------------
__global__ __launch_bounds__(256)
void k6_pass1(const u16* __restrict__ kk, const u16* __restrict__ kki,
              const u16* __restrict__ vT, u16* __restrict__ vfT, u16* __restrict__ vbT,
              const float* __restrict__ csbs, const float* __restrict__ part,
              const u16* __restrict__ rb, const u16* __restrict__ kb,
              u16* __restrict__ rfb, u16* __restrict__ rbb,
              u16* __restrict__ kfb, u16* __restrict__ kbw) {
  __shared__ u16 Kt[2][4096], Vt[2][4096], St[4096];
  int wg = blockIdx.x;
  int tid = threadIdx.x;
  if (wg >= 1024) {
    int bc = (wg - 1024) * 4 + (tid >> 6);
    int bh = bc >> 4, c = bc & 15;
    int lane = tid & 63;
    size_t hb = (size_t)bh * TT * KK;
    float run = 0.f, csb512 = 0.f;
    for (int cc = 0; cc < 16; ++cc) {
      float pvv = part[((size_t)bh * 16 + cc) * 64 + lane];
      if (cc < c) run += pvv;
      if (cc < 8) csb512 += pvv;
    }
    float wh512 = csbs[hb + (size_t)512 * KK + lane];
    float cs512 = csb512 + wh512;
    size_t base = hb + (size_t)c * 64 * KK + lane;
    float cs = run;
    for (int i = 0; i < 64; ++i) {
      size_t g = base + (size_t)i * KK;
      float wh = csbs[g];
      cs += wh;
      float cf = fminf(fmaxf(cs - cs512, -60.f), 60.f);
      float cb = fminf(fmaxf((cs - wh) - csb512, -60.f), 60.f);
      float rvf = bf2f(rb[g]);
      float kvf = bf2f(kb[g]);
      rfb[g] = f2bf(rvf * __expf(cf));
      kfb[g] = f2bf(kvf * __expf(-cf));
      rbb[g] = f2bf(rvf * __expf(-cb));
      kbw[g] = f2bf(kvf * __expf(cb));
    }
    return;
  }
  int dir = (wg >= 512);
  int w0 = dir ? wg - 512 : wg;
  int bh = w0 & 31, it = w0 >> 5, i0 = it * 64;
  size_t hb = (size_t)bh * 65536;
  int w = tid >> 6, lane = tid & 63;
  int iw = i0 + w * 16;
  int row = iw + (lane & 15), ko = (lane >> 4) * 8;
  short8 a0 = *(const short8*)(kki + hb + (size_t)row * 64 + ko);
  short8 a1 = *(const short8*)(kki + hb + (size_t)row * 64 + 32 + ko);
  f32x4 acc[4];
#pragma unroll
  for (int c = 0; c < 4; ++c) acc[c] = {0.f, 0.f, 0.f, 0.f};
  int s0 = dir ? it : 0;
  int nph = dir ? 16 - it : it + 1;
  SReg sr, nx;
  sload<64, 1024>(kk + hb + (size_t)s0 * 4096, vT + hb + s0 * 64, sr);
  swrite(Kt[0], Vt[0], sr);
  __syncthreads();
  for (int p = 0; p < nph; ++p) {
    int s = s0 + p;
    int cur = p & 1;
    if (p < nph - 1)
      sload<64, 1024>(kk + hb + (size_t)(s + 1) * 4096, vT + hb + (s + 1) * 64, nx);
    f32x4 sv[4];
    smm(a0, a1, Kt[cur], sv, lane);
    if (s == it) {
      if (dir) store_S<2>(sv, St, lane, w);
      else store_S<1>(sv, St, lane, w);
    } else {
      store_S<0>(sv, St, lane, w);
    }
    pv(St, Vt[cur], acc, lane, w);
    if (p < nph - 1) swrite(Kt[cur ^ 1], Vt[cur ^ 1], nx);
    __syncthreads();
  }
  u16* dst = dir ? vbT : vfT;
#pragma unroll
  for (int cf = 0; cf < 4; ++cf) {
    int c = cf * 16 + (lane & 15);
    int i = iw + (lane >> 4) * 4;
    size_t g = hb + (size_t)c * 1024 + i;
    short4v vv = *(const short4v*)(vT + g);
    u16 o1[4];
#pragma unroll
    for (int r = 0; r < 4; ++r)
      o1[r] = f2bf(bf2f((u16)vv[r]) - acc[cf][r]);
    *(short4v*)(dst + g) = *(short4v*)o1;
  }
}

// ---------------- K7: pass 2, fwd/bwd split -> partial bf16 outputs yf/yb ----------------
__global__ __launch_bounds__(256)
void k7_pass2(const u16* __restrict__ rfb, const u16* __restrict__ rbb,
              const u16* __restrict__ kfb, const u16* __restrict__ kbw,
              const u16* __restrict__ vfT, const u16* __restrict__ vbT,
              u16* __restrict__ yf, u16* __restrict__ yb) {
  __shared__ u16 Kt[2][4096], Vt[2][4096], St[4096];
  int wg = blockIdx.x;
  int dir = (wg >= 512);
  int w0 = dir ? wg - 512 : wg;
  int bh = w0 & 31, it = w0 >> 5, i0 = it * 64;
  size_t hb = (size_t)bh * 65536;
  int tid = threadIdx.x, w = tid >> 6, lane = tid & 63;
  int iw = i0 + w * 16;
  int row = iw + (lane & 15), ko = (lane >> 4) * 8;
  const u16* rp = dir ? rbb : rfb;
  const u16* kp = dir ? kbw : kfb;
  const u16* vp = dir ? vbT : vfT;
  short8 a0 = *(const short8*)(rp + hb + (size_t)row * 64 + ko);
  short8 a1 = *(const short8*)(rp + hb + (size_t)row * 64 + 32 + ko);
  f32x4 acc[4];
#pragma unroll
  for (int c = 0; c < 4; ++c) acc[c] = {0.f, 0.f, 0.f, 0.f};
  int s0 = dir ? it : 0;
  int nph = dir ? 16 - it : it + 1;
  SReg sr, nx;
  sload<64, 1024>(kp + hb + (size_t)s0 * 4096, vp + hb + s0 * 64, sr);
  swrite(Kt[0], Vt[0], sr);
  __syncthreads();
  for (int p = 0; p < nph; ++p) {
    int s = s0 + p;
    int cur = p & 1;
    if (p < nph - 1)
      sload<64, 1024>(kp + hb + (size_t)(s + 1) * 4096, vp + hb + (s + 1) * 64, nx);
    f32x4 sv[4];
    smm(a0, a1, Kt[cur], sv, lane);
    if (s == it) {
      if (dir) store_S<2>(sv, St, lane, w);
      else store_S<3>(sv, St, lane, w);
    } else {
      store_S<0>(sv, St, lane, w);
    }
    pv(St, Vt[cur], acc, lane, w);
    if (p < nph - 1) swrite(Kt[cur ^ 1], Vt[cur ^ 1], nx);
    __syncthreads();
  }
  u16* y = dir ? yb : yf;
#pragma unroll
  for (int cf = 0; cf < 4; ++cf) {
    int c = cf * 16 + (lane & 15);
#pragma unroll
    for (int r = 0; r < 4; ++r) {
      int i = iw + (lane >> 4) * 4 + r;
      y[hb + (size_t)i * 64 + c] = f2bf(acc[cf][r]);
    }
  }
}

// ---------------- K8: GroupNorm over yf+yb (bf16 partials), * ln + bias, * g -> bf16 ----------------
__global__ __launch_bounds__(256)
void k8_gn2(const u16* __restrict__ yf, const u16* __restrict__ yb,
            const u16* __restrict__ g, const float* __restrict__ lnw,
            const float* __restrict__ lnb, u16* __restrict__ outb) {
  int bt = blockIdx.x;
  int b = bt >> 10, t = bt & 1023;
  int wv = threadIdx.x >> 6, lane = threadIdx.x & 63;
  for (int h = wv; h < HH; h += 4) {
    size_t idx = (((size_t)(b * HH + h)) * TT + t) * KK + lane;
    float v = bf2f(yf[idx]) + bf2f(yb[idx]);
    float s1 = v, s2 = v * v;
#pragma unroll
    for (int off = 32; off > 0; off >>= 1) {
      s1 += __shfl_xor(s1, off);
      s2 += __shfl_xor(s2, off);
    }
    float mu = s1 * (1.f / 64.f);
    float var = s2 * (1.f / 64.f) - mu * mu;
    float xn = (v - mu) * rsqrtf(var + 6.4e-4f);
    int d = h * 64 + lane;
    float o = xn * lnw[d] + lnb[d];
    outb[(size_t)bt * DD + d] = f2bf(o * bf2f(g[(size_t)bt * DD + d]));
  }
}

extern "C" void kernel_launch(void* const* d_in, const int* in_sizes, int n_in,
                              void* d_out, int out_size, void* d_ws, size_t ws_size,
                              hipStream_t stream) {
  const float* x      = (const float*)d_in[0];
  const float* maa_x  = (const float*)d_in[1];
  const float* maa_w  = (const float*)d_in[2];
  const float* maa_k  = (const float*)d_in[3];
  const float* maa_v  = (const float*)d_in[4];
  const float* maa_r  = (const float*)d_in[5];
  const float* maa_g  = (const float*)d_in[6];
  const float* maa_a  = (const float*)d_in[7];
  const float* w1mix  = (const float*)d_in[8];
  const float* w2mix  = (const float*)d_in[9];
  const float* tdecay = (const float*)d_in[10];
  const float* wdec1  = (const float*)d_in[11];
  const float* wdec2  = (const float*)d_in[12];
  const float* a0     = (const float*)d_in[13];
  const float* a1     = (const float*)d_in[14];
  const float* a2     = (const float*)d_in[15];
  const float* k_k    = (const float*)d_in[16];
  const float* k_a    = (const float*)d_in[17];
  const float* W_r    = (const float*)d_in[18];
  const float* W_k    = (const float*)d_in[19];
  const float* W_v    = (const float*)d_in[20];
  const float* W_g    = (const float*)d_in[21];
  const float* W_o    = (const float*)d_in[22];
  const float* lnw    = (const float*)d_in[23];
  const float* lnb    = (const float*)d_in[24];
  float* out = (float*)d_out;

  const size_t NEf = NE;
  float* F = (float*)d_ws;
  u16*   xxx_b  = (u16*)F;              // 2048x1024 bf16 (first half of slot 0)
  u16*   dxb    = ((u16*)F) + NE;       // 2048x1024 bf16 (second half of slot 0)
  u16*   xw_b   = (u16*)(F + 1 * NEf);  // bf16; slot later reused: rfb/rbb
  u16*   xa_b   = (u16*)(F + 2 * NEf);  // bf16; slot later reused: kfb/kbw
  float* csbsb  = F + 4 * NEf;
  float* P3     = F + 3 * NEf;     // consumed by reduce8b
  float* PpartW = F + 3 * NEf;
  float* PpartA = F + 4 * NEf;     // dead before gemm_k2b writes csbsb
  u16*   yfb    = (u16*)(F + 3 * NEf);  // PpartW dead after reduce8_pairb; k7 fwd partial bf16
  u16*   ybb    = (u16*)(F + 5 * NEf);  // k7 bwd partial bf16
  u16*   gb     = (u16*)(F + 6 * NEf);            // gate bf16
  u16*   hmixb  = (u16*)(F + 7 * NEf);            // 2048x192 bf16
  u16*   hdec_b = (u16*)(F + 7 * NEf + 524288);   // 2048x64 bf16
  u16*   ha_b   = (u16*)(F + 7 * NEf + 786432);   // 2048x64 bf16
  float* partb  = F + 7 * NEf + 917504;           // 32768 floats
  u16*   W1t    = (u16*)(F + 7 * NEf + 1048576);  // 192x1024 bf16
  u16*   wdec2t = (u16*)(F + 7 * NEf + 1146880);  // 1024x64 bf16
  u16*   a2t    = (u16*)(F + 7 * NEf + 1179648);  // 1024x64 bf16
  u16*   wdec1t = (u16*)(F + 7 * NEf + 1212416);  // 64x1024 bf16
  u16*   a1t    = (u16*)(F + 7 * NEf + 1245184);  // 64x1024 bf16
  u16*   W2t    = (u16*)(F + 7 * NEf + 1966080);  // 6x1024x32 bf16 (ends < 8*NE)
  u16* rfb = (u16*)xw_b;
  u16* rbb = rfb + NEf;
  u16* kfb = (u16*)xa_b;
  u16* kbw = kfb + NEf;
  u16* U = (u16*)(F + 8 * NEf);
  u16* xr_b = U + 0 * NEf;
  u16* xk_b = U + 1 * NEf;
  u16* xv_b = U + 2 * NEf;
  u16* xg_b = U + 3 * NEf;
  u16* rbuf = U + 4 * NEf;
  u16* kbuf = U + 5 * NEf;
  u16* vT   = U + 6 * NEf;
  u16* kkb  = U + 7 * NEf;
  u16* kkib = U + 8 * NEf;
  u16* vfT  = U + 9 * NEf;
  u16* vbT  = U + 10 * NEf;
  u16* gnb  = U + 11 * NEf;
  u16* WtR  = U + 12 * NEf;
  u16* WtK  = U + 12 * NEf + 1048576;
  u16* WtV  = U + 12 * NEf + 2097152;
  u16* WtG  = U + 12 * NEf + 3145728;
  u16* WtO  = U + 12 * NEf + 4194304;

  dim3 blk(256);

  pre<<<2256, blk, 0, stream>>>(w2mix, W2t, w1mix, W1t, wdec2, a2, wdec2t, a2t,
                                wdec1, a1, wdec1t, a1t, x, maa_x, xxx_b, dxb);

  hmix_g<<<1664, blk, 0, stream>>>(W_r, W_k, W_v, W_g, W_o,
                                   WtR, WtK, WtV, WtG, WtO,
                                   xxx_b, W1t, P3);
  reduce8b<<<1536, blk, 0, stream>>>(P3, hmixb, 393216);

  mixg<<<dim3(8, 16, 6), blk, 0, stream>>>(hmixb, W2t, x, dxb,
                                           maa_w, maa_k, maa_v, maa_r, maa_g, maa_a,
                                           xw_b, xa_b, xk_b, xv_b, xr_b, xg_b);

  gemm_bf4<<<1280, blk, 0, stream>>>(xr_b, xk_b, xv_b, xg_b,
                                     WtR, WtK, WtV, WtG,
                                     rbuf, kbuf, vT, gb,
                                     xw_b, wdec1t, PpartW, xa_b, a1t, PpartA);

  reduce8_pairb<<<dim3(512, 2), blk, 0, stream>>>(PpartW, PpartA, hdec_b, ha_b);

  gemm_k2b<<<dim3(16, 16, 2), blk, 0, stream>>>(hdec_b, wdec2t, tdecay, csbsb, partb,
                                                ha_b, a2t, a0,
                                                kbuf, kkb, kkib, k_k, k_a);

  k6_pass1<<<1152, blk, 0, stream>>>(kkb, kkib, vT, vfT, vbT,
                                     csbsb, partb, rbuf, kbuf,
                                     rfb, rbb, kfb, kbw);
  k7_pass2<<<1024, blk, 0, stream>>>(rfb, rbb, kfb, kbw, vfT, vbT, yfb, ybb);
  k8_gn2<<<NBT, blk, 0, stream>>>(yfb, ybb, gb, lnw, lnb, gnb);
  gemm_bfo<<<256, blk, 0, stream>>>(gnb, WtO, out);
}